// Round 1
// baseline (494.772 us; speedup 1.0000x reference)
//
#include <hip/hip_runtime.h>
#include <hip/hip_bf16.h>
#include <math.h>

#define T_TOK 4096
#define D_MODEL 768
#define H_HEADS 12
#define DH 64
#define SEG 512
#define NSEG 8
#define QKV_LD 2304   // 3*D

// ---------------- SGEMM: C[M,N] = A[M,K] @ B[K,N], fp32, row-major ----------
#define BM 128
#define BN 128
#define BK 8

__global__ __launch_bounds__(256) void sgemm_kernel(const float* __restrict__ A,
                                                    const float* __restrict__ B,
                                                    float* __restrict__ C,
                                                    int M, int N, int K) {
    __shared__ float As[BK][BM];
    __shared__ float Bs[BK][BN];
    const int bx = blockIdx.x;  // N tile
    const int by = blockIdx.y;  // M tile
    const int tid = threadIdx.x;
    const int tx = tid & 15;    // 0..15
    const int ty = tid >> 4;    // 0..15

    const float* Ab = A + (size_t)by * BM * K;
    const float* Bb = B + (size_t)bx * BN;

    float acc[8][8];
#pragma unroll
    for (int i = 0; i < 8; ++i)
#pragma unroll
        for (int j = 0; j < 8; ++j) acc[i][j] = 0.f;

    const int arow = tid >> 1;        // 0..127
    const int acol = (tid & 1) * 4;   // 0 or 4
    const int brow = tid >> 5;        // 0..7
    const int bcol = (tid & 31) * 4;  // 0..124

    for (int k0 = 0; k0 < K; k0 += BK) {
        float4 av = *(const float4*)(Ab + (size_t)arow * K + k0 + acol);
        float4 bv = *(const float4*)(Bb + (size_t)(k0 + brow) * N + bcol);
        __syncthreads();
        As[acol + 0][arow] = av.x;
        As[acol + 1][arow] = av.y;
        As[acol + 2][arow] = av.z;
        As[acol + 3][arow] = av.w;
        *(float4*)(&Bs[brow][bcol]) = bv;
        __syncthreads();
#pragma unroll
        for (int k = 0; k < BK; ++k) {
            float a0[4], a1[4], b0[4], b1[4];
            *(float4*)a0 = *(const float4*)(&As[k][ty * 4]);
            *(float4*)a1 = *(const float4*)(&As[k][64 + ty * 4]);
            *(float4*)b0 = *(const float4*)(&Bs[k][tx * 4]);
            *(float4*)b1 = *(const float4*)(&Bs[k][64 + tx * 4]);
#pragma unroll
            for (int i = 0; i < 4; ++i)
#pragma unroll
                for (int j = 0; j < 4; ++j) {
                    acc[i][j]         += a0[i] * b0[j];
                    acc[i][j + 4]     += a0[i] * b1[j];
                    acc[i + 4][j]     += a1[i] * b0[j];
                    acc[i + 4][j + 4] += a1[i] * b1[j];
                }
        }
    }

    float* Cb = C + (size_t)(by * BM) * N + (size_t)bx * BN;
#pragma unroll
    for (int i = 0; i < 4; ++i) {
        int r0 = ty * 4 + i;
        int r1 = 64 + ty * 4 + i;
        *(float4*)(Cb + (size_t)r0 * N + tx * 4)      = make_float4(acc[i][0], acc[i][1], acc[i][2], acc[i][3]);
        *(float4*)(Cb + (size_t)r0 * N + 64 + tx * 4) = make_float4(acc[i][4], acc[i][5], acc[i][6], acc[i][7]);
        *(float4*)(Cb + (size_t)r1 * N + tx * 4)      = make_float4(acc[i + 4][0], acc[i + 4][1], acc[i + 4][2], acc[i + 4][3]);
        *(float4*)(Cb + (size_t)r1 * N + 64 + tx * 4) = make_float4(acc[i + 4][4], acc[i + 4][5], acc[i + 4][6], acc[i + 4][7]);
    }
}

// ---------------- RoPE (NeoX) in-place on q and k slices of qkv -------------
__global__ __launch_bounds__(256) void rope_kernel(float* __restrict__ qkv,
                                                   const int* __restrict__ pos_ids) {
    int idx = blockIdx.x * 256 + threadIdx.x;  // over T*H*32
    if (idx >= T_TOK * H_HEADS * 32) return;
    int i = idx & 31;
    int h = (idx >> 5) % H_HEADS;
    int t = idx / (H_HEADS * 32);

    float pos = (float)pos_ids[t];
    // inv_freq = theta^(-i/32)
    float inv_freq = powf(160000.0f, -(float)i / 32.0f);
    float f = pos * inv_freq;
    float s, c;
    sincosf(f, &s, &c);

    float* q = qkv + (size_t)t * QKV_LD + h * DH + i;
    float x1 = q[0], x2 = q[32];
    q[0]  = x1 * c - x2 * s;
    q[32] = x2 * c + x1 * s;

    float* k = q + D_MODEL;
    x1 = k[0]; x2 = k[32];
    k[0]  = x1 * c - x2 * s;
    k[32] = x2 * c + x1 * s;
}

// ---------------- Fused segment attention -----------------------------------
// grid: (qtile=8, head=12, seg=8), block 256 threads.
// Each block: 64 q-rows of one (seg, head); iterate 8 k-tiles of 64, online softmax.
#define LDT 68

__global__ __launch_bounds__(256) void attn_kernel(const float* __restrict__ qkv,
                                                   float* __restrict__ attn_out) {
    __shared__ float Qs[64][LDT];   // Qs[row][d]  (pre-scaled by 1/8)
    __shared__ float Kt[64][LDT];   // Kt[d][kcol] (transposed K tile)
    __shared__ float Vs[64][LDT];   // Vs[kcol][d]
    __shared__ float Ss[64][LDT];   // P tile

    const int tid = threadIdx.x;
    const int qt = blockIdx.x, h = blockIdx.y, seg = blockIdx.z;
    const int row = tid >> 2;   // 0..63
    const int grp = tid & 3;    // 0..3
    const int c0 = grp * 16;    // col group for scores / dim group for PV

    const int qbase = seg * SEG + qt * 64;
    const int kbase0 = seg * SEG;

    // load Q tile (scaled)
#pragma unroll
    for (int j = 0; j < 4; ++j) {
        int idx = j * 256 + tid;      // float4 slot 0..1023
        int r = idx >> 4;
        int d = (idx & 15) * 4;
        float4 v = *(const float4*)(qkv + (size_t)(qbase + r) * QKV_LD + h * DH + d);
        v.x *= 0.125f; v.y *= 0.125f; v.z *= 0.125f; v.w *= 0.125f;
        *(float4*)(&Qs[r][d]) = v;
    }

    float m_run = -3.0e38f, l_run = 0.f;
    float o[16];
#pragma unroll
    for (int i = 0; i < 16; ++i) o[i] = 0.f;

    for (int kt = 0; kt < 8; ++kt) {
        const int kb = kbase0 + kt * 64;
        __syncthreads();   // prior-iteration PV reads done
        // stage K^T and V
#pragma unroll
        for (int j = 0; j < 4; ++j) {
            int idx = j * 256 + tid;
            int kc = idx >> 4;
            int d = (idx & 15) * 4;
            const float* base = qkv + (size_t)(kb + kc) * QKV_LD + h * DH + d;
            float4 kv = *(const float4*)(base + D_MODEL);
            Kt[d + 0][kc] = kv.x;
            Kt[d + 1][kc] = kv.y;
            Kt[d + 2][kc] = kv.z;
            Kt[d + 3][kc] = kv.w;
            float4 vv = *(const float4*)(base + 2 * D_MODEL);
            *(float4*)(&Vs[kc][d]) = vv;
        }
        __syncthreads();

        // scores: s[c] = (q/8) . K[:,c0+c]
        float s[16];
#pragma unroll
        for (int c = 0; c < 16; ++c) s[c] = 0.f;
#pragma unroll 4
        for (int kk = 0; kk < 64; ++kk) {
            float qv = Qs[row][kk];
            const float* kp = &Kt[kk][c0];
            float4 k0 = *(const float4*)(kp);
            float4 k1 = *(const float4*)(kp + 4);
            float4 k2 = *(const float4*)(kp + 8);
            float4 k3 = *(const float4*)(kp + 12);
            s[0]  += qv * k0.x; s[1]  += qv * k0.y; s[2]  += qv * k0.z; s[3]  += qv * k0.w;
            s[4]  += qv * k1.x; s[5]  += qv * k1.y; s[6]  += qv * k1.z; s[7]  += qv * k1.w;
            s[8]  += qv * k2.x; s[9]  += qv * k2.y; s[10] += qv * k2.z; s[11] += qv * k2.w;
            s[12] += qv * k3.x; s[13] += qv * k3.y; s[14] += qv * k3.z; s[15] += qv * k3.w;
        }

        // online softmax update
        float mx = s[0];
#pragma unroll
        for (int c = 1; c < 16; ++c) mx = fmaxf(mx, s[c]);
        mx = fmaxf(mx, __shfl_xor(mx, 1));
        mx = fmaxf(mx, __shfl_xor(mx, 2));
        float mnew = fmaxf(m_run, mx);
        float corr = expf(m_run - mnew);

        float p[16];
        float lsum = 0.f;
#pragma unroll
        for (int c = 0; c < 16; ++c) {
            p[c] = expf(s[c] - mnew);
            lsum += p[c];
        }
        lsum += __shfl_xor(lsum, 1);
        lsum += __shfl_xor(lsum, 2);
        l_run = l_run * corr + lsum;
        m_run = mnew;
#pragma unroll
        for (int i = 0; i < 16; ++i) o[i] *= corr;
#pragma unroll
        for (int c = 0; c < 16; ++c) Ss[row][c0 + c] = p[c];
        __syncthreads();

        // PV: o[dd] += sum_kc P[row][kc] * V[kc][c0+dd]
#pragma unroll 4
        for (int kc = 0; kc < 64; ++kc) {
            float pv = Ss[row][kc];
            const float* vp = &Vs[kc][c0];
            float4 v0 = *(const float4*)(vp);
            float4 v1 = *(const float4*)(vp + 4);
            float4 v2 = *(const float4*)(vp + 8);
            float4 v3 = *(const float4*)(vp + 12);
            o[0]  += pv * v0.x; o[1]  += pv * v0.y; o[2]  += pv * v0.z; o[3]  += pv * v0.w;
            o[4]  += pv * v1.x; o[5]  += pv * v1.y; o[6]  += pv * v1.z; o[7]  += pv * v1.w;
            o[8]  += pv * v2.x; o[9]  += pv * v2.y; o[10] += pv * v2.z; o[11] += pv * v2.w;
            o[12] += pv * v3.x; o[13] += pv * v3.y; o[14] += pv * v3.z; o[15] += pv * v3.w;
        }
    }

    float inv = 1.0f / l_run;
#pragma unroll
    for (int i = 0; i < 16; ++i) o[i] *= inv;

    int t = qbase + row;
    float* op = attn_out + (size_t)t * D_MODEL + h * DH + c0;
    *(float4*)(op + 0)  = make_float4(o[0], o[1], o[2], o[3]);
    *(float4*)(op + 4)  = make_float4(o[4], o[5], o[6], o[7]);
    *(float4*)(op + 8)  = make_float4(o[8], o[9], o[10], o[11]);
    *(float4*)(op + 12) = make_float4(o[12], o[13], o[14], o[15]);
}

// ---------------------------------------------------------------------------
extern "C" void kernel_launch(void* const* d_in, const int* in_sizes, int n_in,
                              void* d_out, int out_size, void* d_ws, size_t ws_size,
                              hipStream_t stream) {
    const float* hidden = (const float*)d_in[0];   // T x D
    const float* Wqkv   = (const float*)d_in[1];   // D x 3D
    const float* Wo     = (const float*)d_in[2];   // D x D
    const int*   pos    = (const int*)d_in[3];     // T

    float* qkv      = (float*)d_ws;                                  // T x 3D
    float* attn_out = (float*)((char*)d_ws + (size_t)T_TOK * QKV_LD * sizeof(float)); // T x D
    float* out      = (float*)d_out;

    // 1) qkv = hidden @ Wqkv
    sgemm_kernel<<<dim3(QKV_LD / BN, T_TOK / BM), 256, 0, stream>>>(
        hidden, Wqkv, qkv, T_TOK, QKV_LD, D_MODEL);

    // 2) RoPE in-place on q,k
    rope_kernel<<<(T_TOK * H_HEADS * 32 + 255) / 256, 256, 0, stream>>>(qkv, pos);

    // 3) segment attention
    attn_kernel<<<dim3(SEG / 64, H_HEADS, NSEG), 256, 0, stream>>>(qkv, attn_out);

    // 4) out = attn_out @ Wo
    sgemm_kernel<<<dim3(D_MODEL / BN, T_TOK / BM), 256, 0, stream>>>(
        attn_out, Wo, out, T_TOK, D_MODEL, D_MODEL);
}

// Round 2
// 329.587 us; speedup vs baseline: 1.5012x; 1.5012x over previous
//
#include <hip/hip_runtime.h>
#include <hip/hip_bf16.h>
#include <math.h>

#define T_TOK 4096
#define D_MODEL 768
#define H_HEADS 12
#define DH 64
#define SEG 512
#define NSEG 8
#define QKV_LD 2304   // 3*D
#define KP 2304       // split-K length = 3*768

typedef __bf16 bf16x8_t __attribute__((ext_vector_type(8)));
typedef float f32x4_t __attribute__((ext_vector_type(4)));

// ---------------- split-bf16 MFMA GEMM --------------------------------------
// C[M,N] fp32 += A'[M,KP] (bf16 [hi|hi|lo]) @ B't[N,KP]^T (bf16 rows [hi|lo|hi])
#define GBM 128
#define GBN 128
#define GBK 64

__global__ __launch_bounds__(256) void gemm_bf16s(const __hip_bfloat16* __restrict__ A,
                                                  const __hip_bfloat16* __restrict__ Bt,
                                                  float* __restrict__ C,
                                                  int M, int N, int K) {
    __shared__ __hip_bfloat16 As[GBM * GBK];
    __shared__ __hip_bfloat16 Bs[GBN * GBK];
    const int tid = threadIdx.x;
    const int lane = tid & 63;
    const int wid = tid >> 6;          // 0..3
    const int wr = wid >> 1, wc = wid & 1;
    const int m0 = blockIdx.y * GBM;
    const int n0 = blockIdx.x * GBN;

    f32x4_t acc[4][4];
#pragma unroll
    for (int i = 0; i < 4; ++i)
#pragma unroll
        for (int j = 0; j < 4; ++j) acc[i][j] = (f32x4_t){0.f, 0.f, 0.f, 0.f};

    const int lr = lane >> 3;        // 0..7: row within 8-row staging group
    const int lc = (lane & 7) * 8;   // 0..56: col (elements)
    const int fr = lane & 15;        // fragment row/col
    const int fk = (lane >> 4) * 8;  // fragment k base

    for (int k0 = 0; k0 < K; k0 += GBK) {
        // stage A and B tiles: each wave stages 32 rows of each, 8 rows/inst
#pragma unroll
        for (int i = 0; i < 4; ++i) {
            const int row = wid * 32 + i * 8;
            const __hip_bfloat16* ga = A + (size_t)(m0 + row + lr) * K + k0 + lc;
            __builtin_amdgcn_global_load_lds(
                (const __attribute__((address_space(1))) void*)ga,
                (__attribute__((address_space(3))) void*)(As + row * GBK), 16, 0, 0);
            const __hip_bfloat16* gb = Bt + (size_t)(n0 + row + lr) * K + k0 + lc;
            __builtin_amdgcn_global_load_lds(
                (const __attribute__((address_space(1))) void*)gb,
                (__attribute__((address_space(3))) void*)(Bs + row * GBK), 16, 0, 0);
        }
        __syncthreads();   // drains vmcnt -> tiles resident

#pragma unroll
        for (int kk = 0; kk < 2; ++kk) {
            bf16x8_t af[4], bfr[4];
#pragma unroll
            for (int mi = 0; mi < 4; ++mi)
                af[mi] = *(const bf16x8_t*)(As + (wr * 64 + mi * 16 + fr) * GBK + kk * 32 + fk);
#pragma unroll
            for (int ni = 0; ni < 4; ++ni)
                bfr[ni] = *(const bf16x8_t*)(Bs + (wc * 64 + ni * 16 + fr) * GBK + kk * 32 + fk);
#pragma unroll
            for (int mi = 0; mi < 4; ++mi)
#pragma unroll
                for (int ni = 0; ni < 4; ++ni)
                    acc[mi][ni] = __builtin_amdgcn_mfma_f32_16x16x32_bf16(
                        af[mi], bfr[ni], acc[mi][ni], 0, 0, 0);
        }
        __syncthreads();   // all waves done reading before next overwrite
    }

    float* Cb = C + (size_t)(m0 + wr * 64) * N + n0 + wc * 64;
#pragma unroll
    for (int mi = 0; mi < 4; ++mi)
#pragma unroll
        for (int ni = 0; ni < 4; ++ni)
#pragma unroll
            for (int j = 0; j < 4; ++j) {
                int r = mi * 16 + (lane >> 4) * 4 + j;
                Cb[(size_t)r * N + ni * 16 + fr] = acc[mi][ni][j];
            }
}

// ---------------- fp32 -> split-bf16 row conversion: out[M][3K] = [hi|hi|lo] -
__global__ __launch_bounds__(256) void split_rows(const float* __restrict__ in,
                                                  __hip_bfloat16* __restrict__ out,
                                                  int total4, int K) {
    int idx = blockIdx.x * 256 + threadIdx.x;
    if (idx >= total4) return;
    int Kq = K >> 2;
    int m = idx / Kq, c = idx % Kq;
    float4 v = ((const float4*)in)[(size_t)m * Kq + c];
    union { __hip_bfloat16 h[4]; uint64_t u; } H, L;
    H.h[0] = __float2bfloat16(v.x); H.h[1] = __float2bfloat16(v.y);
    H.h[2] = __float2bfloat16(v.z); H.h[3] = __float2bfloat16(v.w);
    L.h[0] = __float2bfloat16(v.x - __bfloat162float(H.h[0]));
    L.h[1] = __float2bfloat16(v.y - __bfloat162float(H.h[1]));
    L.h[2] = __float2bfloat16(v.z - __bfloat162float(H.h[2]));
    L.h[3] = __float2bfloat16(v.w - __bfloat162float(H.h[3]));
    size_t base = (size_t)m * (3 * K) + c * 4;
    *(uint64_t*)(out + base)         = H.u;  // hi
    *(uint64_t*)(out + base + K)     = H.u;  // hi
    *(uint64_t*)(out + base + 2 * K) = L.u;  // lo
}

// ------- fp32 [K][N] -> transposed split-bf16 out[N][3K] = rows [hi|lo|hi] ---
__global__ __launch_bounds__(256) void split_transpose(const float* __restrict__ in,
                                                       __hip_bfloat16* __restrict__ out,
                                                       int N, int K) {
    __shared__ float tile[64][65];
    const int k0 = blockIdx.y * 64;
    const int n0 = blockIdx.x * 64;
    const int tid = threadIdx.x;
    const int rr = tid >> 4;          // 0..15
    const int cc = (tid & 15) * 4;    // 0..60
#pragma unroll
    for (int i = 0; i < 4; ++i) {
        int r = i * 16 + rr;
        float4 v = *(const float4*)(in + (size_t)(k0 + r) * N + n0 + cc);
        tile[r][cc] = v.x; tile[r][cc + 1] = v.y; tile[r][cc + 2] = v.z; tile[r][cc + 3] = v.w;
    }
    __syncthreads();
#pragma unroll
    for (int i = 0; i < 4; ++i) {
        int n = i * 16 + rr;          // output row (original col)
        float x0 = tile[cc + 0][n];
        float x1 = tile[cc + 1][n];
        float x2 = tile[cc + 2][n];
        float x3 = tile[cc + 3][n];
        union { __hip_bfloat16 h[4]; uint64_t u; } H, L;
        H.h[0] = __float2bfloat16(x0); H.h[1] = __float2bfloat16(x1);
        H.h[2] = __float2bfloat16(x2); H.h[3] = __float2bfloat16(x3);
        L.h[0] = __float2bfloat16(x0 - __bfloat162float(H.h[0]));
        L.h[1] = __float2bfloat16(x1 - __bfloat162float(H.h[1]));
        L.h[2] = __float2bfloat16(x2 - __bfloat162float(H.h[2]));
        L.h[3] = __float2bfloat16(x3 - __bfloat162float(H.h[3]));
        size_t base = (size_t)(n0 + n) * (3 * K) + k0 + cc;
        *(uint64_t*)(out + base)         = H.u;  // hi
        *(uint64_t*)(out + base + K)     = L.u;  // lo
        *(uint64_t*)(out + base + 2 * K) = H.u;  // hi
    }
}

// ---------------- RoPE (NeoX) in-place on q and k slices of qkv -------------
__global__ __launch_bounds__(256) void rope_kernel(float* __restrict__ qkv,
                                                   const int* __restrict__ pos_ids) {
    int idx = blockIdx.x * 256 + threadIdx.x;  // over T*H*32
    if (idx >= T_TOK * H_HEADS * 32) return;
    int i = idx & 31;
    int h = (idx >> 5) % H_HEADS;
    int t = idx / (H_HEADS * 32);

    float pos = (float)pos_ids[t];
    float inv_freq = powf(160000.0f, -(float)i / 32.0f);
    float f = pos * inv_freq;
    float s, c;
    sincosf(f, &s, &c);

    float* q = qkv + (size_t)t * QKV_LD + h * DH + i;
    float x1 = q[0], x2 = q[32];
    q[0]  = x1 * c - x2 * s;
    q[32] = x2 * c + x1 * s;

    float* k = q + D_MODEL;
    x1 = k[0]; x2 = k[32];
    k[0]  = x1 * c - x2 * s;
    k[32] = x2 * c + x1 * s;
}

// ---------------- Fused segment attention (fp32) ----------------------------
#define LDT 68

__global__ __launch_bounds__(256) void attn_kernel(const float* __restrict__ qkv,
                                                   float* __restrict__ attn_out) {
    __shared__ float Qs[64][LDT];
    __shared__ float Kt[64][LDT];
    __shared__ float Vs[64][LDT];
    __shared__ float Ss[64][LDT];

    const int tid = threadIdx.x;
    const int qt = blockIdx.x, h = blockIdx.y, seg = blockIdx.z;
    const int row = tid >> 2;
    const int grp = tid & 3;
    const int c0 = grp * 16;

    const int qbase = seg * SEG + qt * 64;
    const int kbase0 = seg * SEG;

#pragma unroll
    for (int j = 0; j < 4; ++j) {
        int idx = j * 256 + tid;
        int r = idx >> 4;
        int d = (idx & 15) * 4;
        float4 v = *(const float4*)(qkv + (size_t)(qbase + r) * QKV_LD + h * DH + d);
        v.x *= 0.125f; v.y *= 0.125f; v.z *= 0.125f; v.w *= 0.125f;
        *(float4*)(&Qs[r][d]) = v;
    }

    float m_run = -3.0e38f, l_run = 0.f;
    float o[16];
#pragma unroll
    for (int i = 0; i < 16; ++i) o[i] = 0.f;

    for (int kt = 0; kt < 8; ++kt) {
        const int kb = kbase0 + kt * 64;
        __syncthreads();
#pragma unroll
        for (int j = 0; j < 4; ++j) {
            int idx = j * 256 + tid;
            int kc = idx >> 4;
            int d = (idx & 15) * 4;
            const float* base = qkv + (size_t)(kb + kc) * QKV_LD + h * DH + d;
            float4 kv = *(const float4*)(base + D_MODEL);
            Kt[d + 0][kc] = kv.x;
            Kt[d + 1][kc] = kv.y;
            Kt[d + 2][kc] = kv.z;
            Kt[d + 3][kc] = kv.w;
            float4 vv = *(const float4*)(base + 2 * D_MODEL);
            *(float4*)(&Vs[kc][d]) = vv;
        }
        __syncthreads();

        float s[16];
#pragma unroll
        for (int c = 0; c < 16; ++c) s[c] = 0.f;
#pragma unroll 4
        for (int kk = 0; kk < 64; ++kk) {
            float qv = Qs[row][kk];
            const float* kp = &Kt[kk][c0];
            float4 k0 = *(const float4*)(kp);
            float4 k1 = *(const float4*)(kp + 4);
            float4 k2 = *(const float4*)(kp + 8);
            float4 k3 = *(const float4*)(kp + 12);
            s[0]  += qv * k0.x; s[1]  += qv * k0.y; s[2]  += qv * k0.z; s[3]  += qv * k0.w;
            s[4]  += qv * k1.x; s[5]  += qv * k1.y; s[6]  += qv * k1.z; s[7]  += qv * k1.w;
            s[8]  += qv * k2.x; s[9]  += qv * k2.y; s[10] += qv * k2.z; s[11] += qv * k2.w;
            s[12] += qv * k3.x; s[13] += qv * k3.y; s[14] += qv * k3.z; s[15] += qv * k3.w;
        }

        float mx = s[0];
#pragma unroll
        for (int c = 1; c < 16; ++c) mx = fmaxf(mx, s[c]);
        mx = fmaxf(mx, __shfl_xor(mx, 1));
        mx = fmaxf(mx, __shfl_xor(mx, 2));
        float mnew = fmaxf(m_run, mx);
        float corr = expf(m_run - mnew);

        float p[16];
        float lsum = 0.f;
#pragma unroll
        for (int c = 0; c < 16; ++c) {
            p[c] = expf(s[c] - mnew);
            lsum += p[c];
        }
        lsum += __shfl_xor(lsum, 1);
        lsum += __shfl_xor(lsum, 2);
        l_run = l_run * corr + lsum;
        m_run = mnew;
#pragma unroll
        for (int i = 0; i < 16; ++i) o[i] *= corr;
#pragma unroll
        for (int c = 0; c < 16; ++c) Ss[row][c0 + c] = p[c];
        __syncthreads();

#pragma unroll 4
        for (int kc = 0; kc < 64; ++kc) {
            float pv = Ss[row][kc];
            const float* vp = &Vs[kc][c0];
            float4 v0 = *(const float4*)(vp);
            float4 v1 = *(const float4*)(vp + 4);
            float4 v2 = *(const float4*)(vp + 8);
            float4 v3 = *(const float4*)(vp + 12);
            o[0]  += pv * v0.x; o[1]  += pv * v0.y; o[2]  += pv * v0.z; o[3]  += pv * v0.w;
            o[4]  += pv * v1.x; o[5]  += pv * v1.y; o[6]  += pv * v1.z; o[7]  += pv * v1.w;
            o[8]  += pv * v2.x; o[9]  += pv * v2.y; o[10] += pv * v2.z; o[11] += pv * v2.w;
            o[12] += pv * v3.x; o[13] += pv * v3.y; o[14] += pv * v3.z; o[15] += pv * v3.w;
        }
    }

    float inv = 1.0f / l_run;
#pragma unroll
    for (int i = 0; i < 16; ++i) o[i] *= inv;

    int t = qbase + row;
    float* op = attn_out + (size_t)t * D_MODEL + h * DH + c0;
    *(float4*)(op + 0)  = make_float4(o[0], o[1], o[2], o[3]);
    *(float4*)(op + 4)  = make_float4(o[4], o[5], o[6], o[7]);
    *(float4*)(op + 8)  = make_float4(o[8], o[9], o[10], o[11]);
    *(float4*)(op + 12) = make_float4(o[12], o[13], o[14], o[15]);
}

// ---------------------------------------------------------------------------
extern "C" void kernel_launch(void* const* d_in, const int* in_sizes, int n_in,
                              void* d_out, int out_size, void* d_ws, size_t ws_size,
                              hipStream_t stream) {
    const float* hidden = (const float*)d_in[0];   // T x D
    const float* Wqkv   = (const float*)d_in[1];   // D x 3D
    const float* Wo     = (const float*)d_in[2];   // D x D
    const int*   pos    = (const int*)d_in[3];     // T

    char* ws = (char*)d_ws;
    float* qkv      = (float*)(ws);                               // T x 2304 fp32
    float* attn_out = (float*)(ws + 37748736);                    // T x 768 fp32
    __hip_bfloat16* Aq    = (__hip_bfloat16*)(ws + 50331648);     // T x 2304 bf16
    __hip_bfloat16* Bq    = (__hip_bfloat16*)(ws + 69206016);     // 2304 x 2304 bf16
    __hip_bfloat16* Bo    = (__hip_bfloat16*)(ws + 79822848);     // 768 x 2304 bf16
    __hip_bfloat16* Aattn = (__hip_bfloat16*)(ws + 83361792);     // T x 2304 bf16
    float* out = (float*)d_out;

    // conversions
    split_rows<<<(T_TOK * 192 + 255) / 256, 256, 0, stream>>>(hidden, Aq, T_TOK * 192, D_MODEL);
    split_transpose<<<dim3(QKV_LD / 64, D_MODEL / 64), 256, 0, stream>>>(Wqkv, Bq, QKV_LD, D_MODEL);
    split_transpose<<<dim3(D_MODEL / 64, D_MODEL / 64), 256, 0, stream>>>(Wo, Bo, D_MODEL, D_MODEL);

    // 1) qkv = hidden @ Wqkv   (split-bf16 MFMA)
    gemm_bf16s<<<dim3(QKV_LD / GBN, T_TOK / GBM), 256, 0, stream>>>(
        Aq, Bq, qkv, T_TOK, QKV_LD, KP);

    // 2) RoPE in-place on q,k
    rope_kernel<<<(T_TOK * H_HEADS * 32 + 255) / 256, 256, 0, stream>>>(qkv, pos);

    // 3) segment attention (fp32)
    attn_kernel<<<dim3(SEG / 64, H_HEADS, NSEG), 256, 0, stream>>>(qkv, attn_out);

    // 4) out = attn_out @ Wo   (split-bf16 MFMA)
    split_rows<<<(T_TOK * 192 + 255) / 256, 256, 0, stream>>>(attn_out, Aattn, T_TOK * 192, D_MODEL);
    gemm_bf16s<<<dim3(D_MODEL / GBN, T_TOK / GBM), 256, 0, stream>>>(
        Aattn, Bo, out, T_TOK, D_MODEL, KP);
}

// Round 3
// 162.261 us; speedup vs baseline: 3.0492x; 2.0312x over previous
//
#include <hip/hip_runtime.h>
#include <hip/hip_bf16.h>
#include <math.h>

#define T_TOK 4096
#define D_MODEL 768
#define H_HEADS 12
#define DH 64
#define SEG 512
#define NSEG 8
#define QKV_LD 2304   // 3*D

typedef __bf16 bf16x8_t __attribute__((ext_vector_type(8)));
typedef float f32x4_t __attribute__((ext_vector_type(4)));

// ---------------- plain bf16 MFMA GEMM: C[M,N] = A[M,K] @ Bt[N,K]^T ---------
#define GBM 128
#define GBN 128
#define GBK 64

__global__ __launch_bounds__(256) void gemm_bf16(const __hip_bfloat16* __restrict__ A,
                                                 const __hip_bfloat16* __restrict__ Bt,
                                                 float* __restrict__ C,
                                                 int M, int N, int K) {
    __shared__ __hip_bfloat16 As[GBM * GBK];
    __shared__ __hip_bfloat16 Bs[GBN * GBK];
    const int tid = threadIdx.x;
    const int lane = tid & 63;
    const int wid = tid >> 6;
    const int wr = wid >> 1, wc = wid & 1;
    const int m0 = blockIdx.y * GBM;
    const int n0 = blockIdx.x * GBN;

    f32x4_t acc[4][4];
#pragma unroll
    for (int i = 0; i < 4; ++i)
#pragma unroll
        for (int j = 0; j < 4; ++j) acc[i][j] = (f32x4_t){0.f, 0.f, 0.f, 0.f};

    const int lr = lane >> 3;
    const int lc = (lane & 7) * 8;
    const int fr = lane & 15;
    const int fk = (lane >> 4) * 8;

    for (int k0 = 0; k0 < K; k0 += GBK) {
#pragma unroll
        for (int i = 0; i < 4; ++i) {
            const int row = wid * 32 + i * 8;
            const __hip_bfloat16* ga = A + (size_t)(m0 + row + lr) * K + k0 + lc;
            __builtin_amdgcn_global_load_lds(
                (const __attribute__((address_space(1))) void*)ga,
                (__attribute__((address_space(3))) void*)(As + row * GBK), 16, 0, 0);
            const __hip_bfloat16* gb = Bt + (size_t)(n0 + row + lr) * K + k0 + lc;
            __builtin_amdgcn_global_load_lds(
                (const __attribute__((address_space(1))) void*)gb,
                (__attribute__((address_space(3))) void*)(Bs + row * GBK), 16, 0, 0);
        }
        __syncthreads();

#pragma unroll
        for (int kk = 0; kk < 2; ++kk) {
            bf16x8_t af[4], bfr[4];
#pragma unroll
            for (int mi = 0; mi < 4; ++mi)
                af[mi] = *(const bf16x8_t*)(As + (wr * 64 + mi * 16 + fr) * GBK + kk * 32 + fk);
#pragma unroll
            for (int ni = 0; ni < 4; ++ni)
                bfr[ni] = *(const bf16x8_t*)(Bs + (wc * 64 + ni * 16 + fr) * GBK + kk * 32 + fk);
#pragma unroll
            for (int mi = 0; mi < 4; ++mi)
#pragma unroll
                for (int ni = 0; ni < 4; ++ni)
                    acc[mi][ni] = __builtin_amdgcn_mfma_f32_16x16x32_bf16(
                        af[mi], bfr[ni], acc[mi][ni], 0, 0, 0);
        }
        __syncthreads();
    }

    float* Cb = C + (size_t)(m0 + wr * 64) * N + n0 + wc * 64;
#pragma unroll
    for (int mi = 0; mi < 4; ++mi)
#pragma unroll
        for (int ni = 0; ni < 4; ++ni)
#pragma unroll
            for (int j = 0; j < 4; ++j) {
                int r = mi * 16 + (lane >> 4) * 4 + j;
                Cb[(size_t)r * N + ni * 16 + fr] = acc[mi][ni][j];
            }
}

// ---------------- fp32 -> bf16 rows -----------------------------------------
__global__ __launch_bounds__(256) void conv_rows(const float* __restrict__ in,
                                                 __hip_bfloat16* __restrict__ out,
                                                 int total4) {
    int i = blockIdx.x * 256 + threadIdx.x;
    if (i >= total4) return;
    float4 v = ((const float4*)in)[i];
    union { __hip_bfloat16 h[4]; ushort4 u; } o;
    o.h[0] = __float2bfloat16(v.x); o.h[1] = __float2bfloat16(v.y);
    o.h[2] = __float2bfloat16(v.z); o.h[3] = __float2bfloat16(v.w);
    ((ushort4*)out)[i] = o.u;
}

// ---------------- fp32 [K][N] -> bf16 [N][K] (transpose-convert) ------------
__global__ __launch_bounds__(256) void conv_transpose(const float* __restrict__ in,
                                                      __hip_bfloat16* __restrict__ out,
                                                      int N, int K) {
    __shared__ float tile[64][65];
    const int k0 = blockIdx.y * 64;
    const int n0 = blockIdx.x * 64;
    const int tid = threadIdx.x;
    const int rr = tid >> 4;
    const int cc = (tid & 15) * 4;
#pragma unroll
    for (int i = 0; i < 4; ++i) {
        int r = i * 16 + rr;
        float4 v = *(const float4*)(in + (size_t)(k0 + r) * N + n0 + cc);
        tile[r][cc] = v.x; tile[r][cc + 1] = v.y; tile[r][cc + 2] = v.z; tile[r][cc + 3] = v.w;
    }
    __syncthreads();
#pragma unroll
    for (int i = 0; i < 4; ++i) {
        int n = i * 16 + rr;
        union { __hip_bfloat16 h[4]; ushort4 u; } o;
        o.h[0] = __float2bfloat16(tile[cc + 0][n]);
        o.h[1] = __float2bfloat16(tile[cc + 1][n]);
        o.h[2] = __float2bfloat16(tile[cc + 2][n]);
        o.h[3] = __float2bfloat16(tile[cc + 3][n]);
        *(ushort4*)(out + (size_t)(n0 + n) * K + k0 + cc) = o.u;
    }
}

// ------- RoPE (NeoX) -> bf16 Qb[h][t][d] (x1/8), Kb[h][t][d] ---------------
__global__ __launch_bounds__(256) void rope_bf16(const float* __restrict__ qkv,
                                                 const int* __restrict__ pos_ids,
                                                 __hip_bfloat16* __restrict__ Qb,
                                                 __hip_bfloat16* __restrict__ Kb) {
    int idx = blockIdx.x * 256 + threadIdx.x;  // T*H*32
    if (idx >= T_TOK * H_HEADS * 32) return;
    int i = idx & 31;
    int h = (idx >> 5) % H_HEADS;
    int t = idx / (H_HEADS * 32);

    float pos = (float)pos_ids[t];
    float inv_freq = powf(160000.0f, -(float)i / 32.0f);
    float f = pos * inv_freq;
    float s, c;
    sincosf(f, &s, &c);

    const float* q = qkv + (size_t)t * QKV_LD + h * DH + i;
    size_t ob = ((size_t)h * T_TOK + t) * DH + i;
    float x1 = q[0], x2 = q[32];
    Qb[ob]      = __float2bfloat16((x1 * c - x2 * s) * 0.125f);
    Qb[ob + 32] = __float2bfloat16((x2 * c + x1 * s) * 0.125f);
    const float* k = q + D_MODEL;
    x1 = k[0]; x2 = k[32];
    Kb[ob]      = __float2bfloat16(x1 * c - x2 * s);
    Kb[ob + 32] = __float2bfloat16(x2 * c + x1 * s);
}

// ------- V slice of qkv -> Vtb[h][seg][d][key] bf16 (transposed) ------------
__global__ __launch_bounds__(256) void v_transpose(const float* __restrict__ qkv,
                                                   __hip_bfloat16* __restrict__ Vtb) {
    __shared__ float tile[64][65];
    const int h = blockIdx.x, seg = blockIdx.y;
    const int tid = threadIdx.x;
    const int key = tid >> 2;
    const int dq = (tid & 3) * 16;
    for (int kb = 0; kb < 8; ++kb) {
        const float* src = qkv + (size_t)(seg * SEG + kb * 64 + key) * QKV_LD + 2 * D_MODEL + h * DH + dq;
        float4 a = ((const float4*)src)[0];
        float4 b = ((const float4*)src)[1];
        float4 c = ((const float4*)src)[2];
        float4 d = ((const float4*)src)[3];
        __syncthreads();
        tile[dq + 0][key] = a.x; tile[dq + 1][key] = a.y; tile[dq + 2][key] = a.z; tile[dq + 3][key] = a.w;
        tile[dq + 4][key] = b.x; tile[dq + 5][key] = b.y; tile[dq + 6][key] = b.z; tile[dq + 7][key] = b.w;
        tile[dq + 8][key] = c.x; tile[dq + 9][key] = c.y; tile[dq + 10][key] = c.z; tile[dq + 11][key] = c.w;
        tile[dq + 12][key] = d.x; tile[dq + 13][key] = d.y; tile[dq + 14][key] = d.z; tile[dq + 15][key] = d.w;
        __syncthreads();
        const int d0 = tid >> 2;
        const int kq = (tid & 3) * 16;
        __hip_bfloat16* dst = Vtb + ((size_t)(h * NSEG + seg) * DH + d0) * SEG + kb * 64 + kq;
#pragma unroll
        for (int x = 0; x < 4; ++x) {
            union { __hip_bfloat16 h2[4]; ushort4 u; } o;
            o.h2[0] = __float2bfloat16(tile[d0][kq + 4 * x + 0]);
            o.h2[1] = __float2bfloat16(tile[d0][kq + 4 * x + 1]);
            o.h2[2] = __float2bfloat16(tile[d0][kq + 4 * x + 2]);
            o.h2[3] = __float2bfloat16(tile[d0][kq + 4 * x + 3]);
            *(ushort4*)(dst + 4 * x) = o.u;
        }
    }
}

// ---------------- MFMA flash attention over 512-token segments --------------
// grid (qt=4, h=12, seg=8), 256 thr = 4 waves. Q-tile 128 rows, K-tile 128.
#define KSL 72    // Ks row stride (elems): 144B -> 4-bank shift/row
#define VSL 136   // Vts/Ps row stride: 272B

__global__ __launch_bounds__(256) void attn_mfma(const __hip_bfloat16* __restrict__ Qb,
                                                 const __hip_bfloat16* __restrict__ Kb,
                                                 const __hip_bfloat16* __restrict__ Vtb,
                                                 __hip_bfloat16* __restrict__ attnb) {
    __shared__ __hip_bfloat16 Ks[128 * KSL];
    __shared__ __hip_bfloat16 Vts[64 * VSL];
    __shared__ __hip_bfloat16 Ps[128 * VSL];
    __shared__ float mrun[128], lrun[128], corr_s[128];
    __shared__ float redmax[2][128], redsum[2][128];

    const int tid = threadIdx.x;
    const int lane = tid & 63;
    const int w = tid >> 6;
    const int wr = w >> 1, wc = w & 1;
    const int l15 = lane & 15;
    const int l4 = lane >> 4;
    const int qt = blockIdx.x, h = blockIdx.y, seg = blockIdx.z;

    if (tid < 128) { mrun[tid] = -3.0e38f; lrun[tid] = 0.f; }

    // Q fragments in registers (pre-scaled by 1/8 in rope_bf16)
    bf16x8_t af[4][2];
    {
        const __hip_bfloat16* qb = Qb + ((size_t)h * T_TOK + seg * SEG + qt * 128 + wr * 64) * DH;
#pragma unroll
        for (int mi = 0; mi < 4; ++mi)
#pragma unroll
            for (int kk = 0; kk < 2; ++kk)
                af[mi][kk] = *(const bf16x8_t*)(qb + (size_t)(mi * 16 + l15) * DH + kk * 32 + l4 * 8);
    }

    f32x4_t acc2[2][4];
#pragma unroll
    for (int i = 0; i < 2; ++i)
#pragma unroll
        for (int j = 0; j < 4; ++j) acc2[i][j] = (f32x4_t){0.f, 0.f, 0.f, 0.f};

    const __hip_bfloat16* kbase = Kb + ((size_t)h * T_TOK + seg * SEG) * DH;
    const __hip_bfloat16* vbase = Vtb + (size_t)(h * NSEG + seg) * DH * SEG;

    for (int kt = 0; kt < 4; ++kt) {
        // ---- stage K[128][64] and Vt[64][128] (reg -> padded LDS) ----
#pragma unroll
        for (int i = 0; i < 4; ++i) {
            int cid = i * 256 + tid;
            int r = cid >> 3, c = cid & 7;
            uint4 kv = *(const uint4*)(kbase + ((size_t)kt * 128 + r) * DH + c * 8);
            *(uint4*)(&Ks[r * KSL + c * 8]) = kv;
            int rv = cid >> 4, cv = cid & 15;
            uint4 vv = *(const uint4*)(vbase + (size_t)rv * SEG + kt * 128 + cv * 8);
            *(uint4*)(&Vts[rv * VSL + cv * 8]) = vv;
        }
        __syncthreads();

        // ---- S = Q K^T (wave (wr,wc) -> 64x64 subtile) ----
        f32x4_t acc[4][4];
#pragma unroll
        for (int i = 0; i < 4; ++i)
#pragma unroll
            for (int j = 0; j < 4; ++j) acc[i][j] = (f32x4_t){0.f, 0.f, 0.f, 0.f};
#pragma unroll
        for (int kk = 0; kk < 2; ++kk) {
            bf16x8_t bfr[4];
#pragma unroll
            for (int ni = 0; ni < 4; ++ni)
                bfr[ni] = *(const bf16x8_t*)(&Ks[(wc * 64 + ni * 16 + l15) * KSL + kk * 32 + l4 * 8]);
#pragma unroll
            for (int mi = 0; mi < 4; ++mi)
#pragma unroll
                for (int ni = 0; ni < 4; ++ni)
                    acc[mi][ni] = __builtin_amdgcn_mfma_f32_16x16x32_bf16(
                        af[mi][kk], bfr[ni], acc[mi][ni], 0, 0, 0);
        }

        // row-max within this wave's 64 cols
#pragma unroll
        for (int mi = 0; mi < 4; ++mi)
#pragma unroll
            for (int j = 0; j < 4; ++j) {
                float m4 = fmaxf(fmaxf(acc[mi][0][j], acc[mi][1][j]),
                                 fmaxf(acc[mi][2][j], acc[mi][3][j]));
                m4 = fmaxf(m4, __shfl_xor(m4, 1));
                m4 = fmaxf(m4, __shfl_xor(m4, 2));
                m4 = fmaxf(m4, __shfl_xor(m4, 4));
                m4 = fmaxf(m4, __shfl_xor(m4, 8));
                if (l15 == 0) redmax[wc][wr * 64 + mi * 16 + l4 * 4 + j] = m4;
            }
        __syncthreads();   // A

        // ---- softmax: P = exp(S - m_new), partial row sums, corr ----
#pragma unroll
        for (int mi = 0; mi < 4; ++mi)
#pragma unroll
            for (int j = 0; j < 4; ++j) {
                int r = wr * 64 + mi * 16 + l4 * 4 + j;
                float mt = fmaxf(redmax[0][r], redmax[1][r]);
                float mold = mrun[r];
                float mnew = fmaxf(mold, mt);
                float rowsum = 0.f;
#pragma unroll
                for (int ni = 0; ni < 4; ++ni) {
                    float p = __expf(acc[mi][ni][j] - mnew);
                    rowsum += p;
                    Ps[r * VSL + wc * 64 + ni * 16 + l15] = __float2bfloat16(p);
                }
                rowsum += __shfl_xor(rowsum, 1);
                rowsum += __shfl_xor(rowsum, 2);
                rowsum += __shfl_xor(rowsum, 4);
                rowsum += __shfl_xor(rowsum, 8);
                if (l15 == 0) {
                    redsum[wc][r] = rowsum;
                    if (wc == 0) corr_s[r] = __expf(mold - mnew);
                }
            }
        __syncthreads();   // B

        // ---- state update (threads 0..127, one row each) ----
        if (tid < 128) {
            int r = tid;
            float mt = fmaxf(redmax[0][r], redmax[1][r]);
            float mold = mrun[r];
            lrun[r] = lrun[r] * corr_s[r] + redsum[0][r] + redsum[1][r];
            mrun[r] = fmaxf(mold, mt);
        }

        // ---- PV: wave w -> rows 32w..32w+31, all 64 dims ----
#pragma unroll
        for (int mi2 = 0; mi2 < 2; ++mi2)
#pragma unroll
            for (int j = 0; j < 4; ++j) {
                float cr = corr_s[w * 32 + mi2 * 16 + l4 * 4 + j];
#pragma unroll
                for (int ni = 0; ni < 4; ++ni) acc2[mi2][ni][j] *= cr;
            }
#pragma unroll
        for (int ks = 0; ks < 4; ++ks) {
            bf16x8_t pa[2], vb[4];
#pragma unroll
            for (int mi2 = 0; mi2 < 2; ++mi2)
                pa[mi2] = *(const bf16x8_t*)(&Ps[(w * 32 + mi2 * 16 + l15) * VSL + ks * 32 + l4 * 8]);
#pragma unroll
            for (int ni = 0; ni < 4; ++ni)
                vb[ni] = *(const bf16x8_t*)(&Vts[(ni * 16 + l15) * VSL + ks * 32 + l4 * 8]);
#pragma unroll
            for (int mi2 = 0; mi2 < 2; ++mi2)
#pragma unroll
                for (int ni = 0; ni < 4; ++ni)
                    acc2[mi2][ni] = __builtin_amdgcn_mfma_f32_16x16x32_bf16(
                        pa[mi2], vb[ni], acc2[mi2][ni], 0, 0, 0);
        }
        __syncthreads();   // C
    }

    // epilogue: normalize and store bf16
#pragma unroll
    for (int mi2 = 0; mi2 < 2; ++mi2)
#pragma unroll
        for (int j = 0; j < 4; ++j) {
            int rl = w * 32 + mi2 * 16 + l4 * 4 + j;
            float inv = 1.0f / lrun[rl];
            size_t t = (size_t)(seg * SEG + qt * 128 + rl);
#pragma unroll
            for (int ni = 0; ni < 4; ++ni)
                attnb[t * D_MODEL + h * DH + ni * 16 + l15] =
                    __float2bfloat16(acc2[mi2][ni][j] * inv);
        }
}

// ---------------------------------------------------------------------------
extern "C" void kernel_launch(void* const* d_in, const int* in_sizes, int n_in,
                              void* d_out, int out_size, void* d_ws, size_t ws_size,
                              hipStream_t stream) {
    const float* hidden = (const float*)d_in[0];
    const float* Wqkv   = (const float*)d_in[1];
    const float* Wo     = (const float*)d_in[2];
    const int*   pos    = (const int*)d_in[3];

    char* ws = (char*)d_ws;
    float* qkv            = (float*)(ws);                       // 37,748,736 B
    __hip_bfloat16* Xb    = (__hip_bfloat16*)(ws + 37748736);   // 6,291,456
    __hip_bfloat16* Wqkvt = (__hip_bfloat16*)(ws + 44040192);   // 3,538,944
    __hip_bfloat16* Wot   = (__hip_bfloat16*)(ws + 47579136);   // 1,179,648
    __hip_bfloat16* Qb    = (__hip_bfloat16*)(ws + 48758784);   // 6,291,456
    __hip_bfloat16* Kb    = (__hip_bfloat16*)(ws + 55050240);   // 6,291,456
    __hip_bfloat16* Vtb   = (__hip_bfloat16*)(ws + 61341696);   // 6,291,456
    __hip_bfloat16* attnb = (__hip_bfloat16*)(ws + 67633152);   // 6,291,456
    float* out = (float*)d_out;

    // conversions
    conv_rows<<<(T_TOK * D_MODEL / 4 + 255) / 256, 256, 0, stream>>>(hidden, Xb, T_TOK * D_MODEL / 4);
    conv_transpose<<<dim3(QKV_LD / 64, D_MODEL / 64), 256, 0, stream>>>(Wqkv, Wqkvt, QKV_LD, D_MODEL);
    conv_transpose<<<dim3(D_MODEL / 64, D_MODEL / 64), 256, 0, stream>>>(Wo, Wot, D_MODEL, D_MODEL);

    // 1) qkv = X @ Wqkv (bf16 MFMA, fp32 out)
    gemm_bf16<<<dim3(QKV_LD / GBN, T_TOK / GBM), 256, 0, stream>>>(
        Xb, Wqkvt, qkv, T_TOK, QKV_LD, D_MODEL);

    // 2) RoPE -> Qb (scaled), Kb ; V -> Vtb (transposed)
    rope_bf16<<<(T_TOK * H_HEADS * 32 + 255) / 256, 256, 0, stream>>>(qkv, pos, Qb, Kb);
    v_transpose<<<dim3(H_HEADS, NSEG), 256, 0, stream>>>(qkv, Vtb);

    // 3) MFMA flash attention per 512-token segment
    attn_mfma<<<dim3(4, H_HEADS, NSEG), 256, 0, stream>>>(Qb, Kb, Vtb, attnb);

    // 4) out = attn @ Wo
    gemm_bf16<<<dim3(D_MODEL / GBN, T_TOK / GBM), 256, 0, stream>>>(
        attnb, Wot, out, T_TOK, D_MODEL, D_MODEL);
}

// Round 4
// 117.277 us; speedup vs baseline: 4.2188x; 1.3836x over previous
//
#include <hip/hip_runtime.h>
#include <hip/hip_bf16.h>
#include <math.h>

#define T_TOK 4096
#define D_MODEL 768
#define H_HEADS 12
#define DH 64
#define SEG 512
#define NSEG 8
#define QKV_LD 2304   // 3*D

typedef __bf16 bf16x8_t __attribute__((ext_vector_type(8)));
typedef float f32x4_t __attribute__((ext_vector_type(4)));
typedef float f32x16_t __attribute__((ext_vector_type(16)));

// ---------------- plain bf16 MFMA GEMM: C[M,N] = A[M,K] @ Bt[N,K]^T ---------
#define GBM 128
#define GBN 128
#define GBK 64

__global__ __launch_bounds__(256) void gemm_bf16(const __hip_bfloat16* __restrict__ A,
                                                 const __hip_bfloat16* __restrict__ Bt,
                                                 float* __restrict__ C,
                                                 int M, int N, int K) {
    __shared__ __hip_bfloat16 As[GBM * GBK];
    __shared__ __hip_bfloat16 Bs[GBN * GBK];
    const int tid = threadIdx.x;
    const int lane = tid & 63;
    const int wid = tid >> 6;
    const int wr = wid >> 1, wc = wid & 1;
    const int m0 = blockIdx.y * GBM;
    const int n0 = blockIdx.x * GBN;

    f32x4_t acc[4][4];
#pragma unroll
    for (int i = 0; i < 4; ++i)
#pragma unroll
        for (int j = 0; j < 4; ++j) acc[i][j] = (f32x4_t){0.f, 0.f, 0.f, 0.f};

    const int lr = lane >> 3;
    const int lc = (lane & 7) * 8;
    const int fr = lane & 15;
    const int fk = (lane >> 4) * 8;

    for (int k0 = 0; k0 < K; k0 += GBK) {
#pragma unroll
        for (int i = 0; i < 4; ++i) {
            const int row = wid * 32 + i * 8;
            const __hip_bfloat16* ga = A + (size_t)(m0 + row + lr) * K + k0 + lc;
            __builtin_amdgcn_global_load_lds(
                (const __attribute__((address_space(1))) void*)ga,
                (__attribute__((address_space(3))) void*)(As + row * GBK), 16, 0, 0);
            const __hip_bfloat16* gb = Bt + (size_t)(n0 + row + lr) * K + k0 + lc;
            __builtin_amdgcn_global_load_lds(
                (const __attribute__((address_space(1))) void*)gb,
                (__attribute__((address_space(3))) void*)(Bs + row * GBK), 16, 0, 0);
        }
        __syncthreads();

#pragma unroll
        for (int kk = 0; kk < 2; ++kk) {
            bf16x8_t af[4], bfr[4];
#pragma unroll
            for (int mi = 0; mi < 4; ++mi)
                af[mi] = *(const bf16x8_t*)(As + (wr * 64 + mi * 16 + fr) * GBK + kk * 32 + fk);
#pragma unroll
            for (int ni = 0; ni < 4; ++ni)
                bfr[ni] = *(const bf16x8_t*)(Bs + (wc * 64 + ni * 16 + fr) * GBK + kk * 32 + fk);
#pragma unroll
            for (int mi = 0; mi < 4; ++mi)
#pragma unroll
                for (int ni = 0; ni < 4; ++ni)
                    acc[mi][ni] = __builtin_amdgcn_mfma_f32_16x16x32_bf16(
                        af[mi], bfr[ni], acc[mi][ni], 0, 0, 0);
        }
        __syncthreads();
    }

    float* Cb = C + (size_t)(m0 + wr * 64) * N + n0 + wc * 64;
#pragma unroll
    for (int mi = 0; mi < 4; ++mi)
#pragma unroll
        for (int ni = 0; ni < 4; ++ni)
#pragma unroll
            for (int j = 0; j < 4; ++j) {
                int r = mi * 16 + (lane >> 4) * 4 + j;
                Cb[(size_t)r * N + ni * 16 + fr] = acc[mi][ni][j];
            }
}

// ---------------- fp32 -> bf16 rows -----------------------------------------
__global__ __launch_bounds__(256) void conv_rows(const float* __restrict__ in,
                                                 __hip_bfloat16* __restrict__ out,
                                                 int total4) {
    int i = blockIdx.x * 256 + threadIdx.x;
    if (i >= total4) return;
    float4 v = ((const float4*)in)[i];
    union { __hip_bfloat16 h[4]; ushort4 u; } o;
    o.h[0] = __float2bfloat16(v.x); o.h[1] = __float2bfloat16(v.y);
    o.h[2] = __float2bfloat16(v.z); o.h[3] = __float2bfloat16(v.w);
    ((ushort4*)out)[i] = o.u;
}

// ---------------- fp32 [K][N] -> bf16 [N][K] (transpose-convert) ------------
__global__ __launch_bounds__(256) void conv_transpose(const float* __restrict__ in,
                                                      __hip_bfloat16* __restrict__ out,
                                                      int N, int K) {
    __shared__ float tile[64][65];
    const int k0 = blockIdx.y * 64;
    const int n0 = blockIdx.x * 64;
    const int tid = threadIdx.x;
    const int rr = tid >> 4;
    const int cc = (tid & 15) * 4;
#pragma unroll
    for (int i = 0; i < 4; ++i) {
        int r = i * 16 + rr;
        float4 v = *(const float4*)(in + (size_t)(k0 + r) * N + n0 + cc);
        tile[r][cc] = v.x; tile[r][cc + 1] = v.y; tile[r][cc + 2] = v.z; tile[r][cc + 3] = v.w;
    }
    __syncthreads();
#pragma unroll
    for (int i = 0; i < 4; ++i) {
        int n = i * 16 + rr;
        union { __hip_bfloat16 h[4]; ushort4 u; } o;
        o.h[0] = __float2bfloat16(tile[cc + 0][n]);
        o.h[1] = __float2bfloat16(tile[cc + 1][n]);
        o.h[2] = __float2bfloat16(tile[cc + 2][n]);
        o.h[3] = __float2bfloat16(tile[cc + 3][n]);
        *(ushort4*)(out + (size_t)(n0 + n) * K + k0 + cc) = o.u;
    }
}

// ------- RoPE (NeoX) -> bf16 Qb[h][t][d] (x1/8), Kb[h][t][d] ---------------
__global__ __launch_bounds__(256) void rope_bf16(const float* __restrict__ qkv,
                                                 const int* __restrict__ pos_ids,
                                                 __hip_bfloat16* __restrict__ Qb,
                                                 __hip_bfloat16* __restrict__ Kb) {
    int idx = blockIdx.x * 256 + threadIdx.x;  // T*H*32
    if (idx >= T_TOK * H_HEADS * 32) return;
    int i = idx & 31;
    int h = (idx >> 5) % H_HEADS;
    int t = idx / (H_HEADS * 32);

    float pos = (float)pos_ids[t];
    float inv_freq = powf(160000.0f, -(float)i / 32.0f);
    float f = pos * inv_freq;
    float s, c;
    sincosf(f, &s, &c);

    const float* q = qkv + (size_t)t * QKV_LD + h * DH + i;
    size_t ob = ((size_t)h * T_TOK + t) * DH + i;
    float x1 = q[0], x2 = q[32];
    Qb[ob]      = __float2bfloat16((x1 * c - x2 * s) * 0.125f);
    Qb[ob + 32] = __float2bfloat16((x2 * c + x1 * s) * 0.125f);
    const float* k = q + D_MODEL;
    x1 = k[0]; x2 = k[32];
    Kb[ob]      = __float2bfloat16(x1 * c - x2 * s);
    Kb[ob + 32] = __float2bfloat16(x2 * c + x1 * s);
}

// ------- V slice of qkv -> Vtb[h][seg][d][key] bf16 (transposed) ------------
__global__ __launch_bounds__(256) void v_transpose(const float* __restrict__ qkv,
                                                   __hip_bfloat16* __restrict__ Vtb) {
    __shared__ float tile[64][65];
    const int h = blockIdx.x, seg = blockIdx.y;
    const int tid = threadIdx.x;
    const int key = tid >> 2;
    const int dq = (tid & 3) * 16;
    for (int kb = 0; kb < 8; ++kb) {
        const float* src = qkv + (size_t)(seg * SEG + kb * 64 + key) * QKV_LD + 2 * D_MODEL + h * DH + dq;
        float4 a = ((const float4*)src)[0];
        float4 b = ((const float4*)src)[1];
        float4 c = ((const float4*)src)[2];
        float4 d = ((const float4*)src)[3];
        __syncthreads();
        tile[dq + 0][key] = a.x; tile[dq + 1][key] = a.y; tile[dq + 2][key] = a.z; tile[dq + 3][key] = a.w;
        tile[dq + 4][key] = b.x; tile[dq + 5][key] = b.y; tile[dq + 6][key] = b.z; tile[dq + 7][key] = b.w;
        tile[dq + 8][key] = c.x; tile[dq + 9][key] = c.y; tile[dq + 10][key] = c.z; tile[dq + 11][key] = c.w;
        tile[dq + 12][key] = d.x; tile[dq + 13][key] = d.y; tile[dq + 14][key] = d.z; tile[dq + 15][key] = d.w;
        __syncthreads();
        const int d0 = tid >> 2;
        const int kq = (tid & 3) * 16;
        __hip_bfloat16* dst = Vtb + ((size_t)(h * NSEG + seg) * DH + d0) * SEG + kb * 64 + kq;
#pragma unroll
        for (int x = 0; x < 4; ++x) {
            union { __hip_bfloat16 h2[4]; ushort4 u; } o;
            o.h2[0] = __float2bfloat16(tile[d0][kq + 4 * x + 0]);
            o.h2[1] = __float2bfloat16(tile[d0][kq + 4 * x + 1]);
            o.h2[2] = __float2bfloat16(tile[d0][kq + 4 * x + 2]);
            o.h2[3] = __float2bfloat16(tile[d0][kq + 4 * x + 3]);
            *(ushort4*)(dst + 4 * x) = o.u;
        }
    }
}

// ---------------- swapped-QK in-register-softmax flash attention ------------
// grid (qt=8, h=12, seg=8), 128 thr = 2 waves; wave owns 32 q-rows.
// S^T = mfma32(K, Q): lane q = lane&31 holds 32 scores in regs.
// O^T = mfma32(V^T, P): column q = lane&31 -> corr is a per-lane scalar.
__device__ __forceinline__ unsigned pk2(float a, float b) {
    unsigned ua = (unsigned)__bfloat16_as_ushort(__float2bfloat16(a));
    unsigned ub = (unsigned)__bfloat16_as_ushort(__float2bfloat16(b));
    return ua | (ub << 16);
}

__global__ __launch_bounds__(128) void attn_mfma(const __hip_bfloat16* __restrict__ Qb,
                                                 const __hip_bfloat16* __restrict__ Kb,
                                                 const __hip_bfloat16* __restrict__ Vtb,
                                                 __hip_bfloat16* __restrict__ attnb) {
    __shared__ __hip_bfloat16 KS[2][64 * 64];
    __shared__ __hip_bfloat16 VS[2][64 * 64];

    const int tid = threadIdx.x;
    const int lane = tid & 63;
    const int w = tid >> 6;        // 0..1
    const int hi = lane >> 5;      // 0/1
    const int l31 = lane & 31;
    const int qt = blockIdx.x, h = blockIdx.y, seg = blockIdx.z;
    const int t0 = seg * SEG + qt * 64 + w * 32;

    const __hip_bfloat16* kb = Kb + ((size_t)h * T_TOK + seg * SEG) * DH;
    const __hip_bfloat16* vb = Vtb + (size_t)(h * NSEG + seg) * DH * SEG;

    // Q fragments (B-operand for QK): frag s holds d = s*16 + hi*8 .. +7
    bf16x8_t qf[4];
    {
        const __hip_bfloat16* qp = Qb + ((size_t)h * T_TOK + t0 + l31) * DH + hi * 8;
#pragma unroll
        for (int s = 0; s < 4; ++s) qf[s] = *(const bf16x8_t*)(qp + s * 16);
    }

    const int gr = lane >> 3;  // granule row within 64-granule block
    const int gc = lane & 7;   // granule col

    // prologue: stage kv tile 0 into buffer 0 (pre-swizzled global source,
    // linear LDS dest; read side XORs the 16B-granule index)
#pragma unroll
    for (int i = 0; i < 4; ++i) {
        int G = i * 128 + w * 64;
        int rk = (G >> 3) + gr;
        const __hip_bfloat16* sk = kb + (size_t)rk * DH + ((gc ^ (rk & 7)) << 3);
        __builtin_amdgcn_global_load_lds(
            (const __attribute__((address_space(1))) void*)sk,
            (__attribute__((address_space(3))) void*)(&KS[0][G * 8]), 16, 0, 0);
        const __hip_bfloat16* sv = vb + (size_t)rk * SEG + ((gc ^ (rk & 7)) << 3);
        __builtin_amdgcn_global_load_lds(
            (const __attribute__((address_space(1))) void*)sv,
            (__attribute__((address_space(3))) void*)(&VS[0][G * 8]), 16, 0, 0);
    }
    __syncthreads();

    f32x16_t ot[2];
#pragma unroll
    for (int n = 0; n < 2; ++n)
#pragma unroll
        for (int r = 0; r < 16; ++r) ot[n][r] = 0.f;
    float mrun = -3.0e38f, lrun = 0.f;

    for (int kv = 0; kv < 8; ++kv) {
        const int bb = kv & 1;
        // stage next kv tile into other buffer (loads fly during compute)
        if (kv < 7) {
#pragma unroll
            for (int i = 0; i < 4; ++i) {
                int G = i * 128 + w * 64;
                int rk = (G >> 3) + gr;
                const __hip_bfloat16* sk = kb + (size_t)((kv + 1) * 64 + rk) * DH + ((gc ^ (rk & 7)) << 3);
                __builtin_amdgcn_global_load_lds(
                    (const __attribute__((address_space(1))) void*)sk,
                    (__attribute__((address_space(3))) void*)(&KS[bb ^ 1][G * 8]), 16, 0, 0);
                const __hip_bfloat16* sv = vb + (size_t)rk * SEG + (kv + 1) * 64 + ((gc ^ (rk & 7)) << 3);
                __builtin_amdgcn_global_load_lds(
                    (const __attribute__((address_space(1))) void*)sv,
                    (__attribute__((address_space(3))) void*)(&VS[bb ^ 1][G * 8]), 16, 0, 0);
            }
        }

        // ---- S^T = K . Q^T  (2 key-tiles of 32 x K-dim 64) ----
        f32x16_t st[2];
#pragma unroll
        for (int t = 0; t < 2; ++t)
#pragma unroll
            for (int r = 0; r < 16; ++r) st[t][r] = 0.f;
#pragma unroll
        for (int s = 0; s < 4; ++s) {
            int gk = s * 2 + hi;
            bf16x8_t k0 = *(const bf16x8_t*)(&KS[bb][l31 * 64 + ((gk ^ (l31 & 7)) << 3)]);
            bf16x8_t k1 = *(const bf16x8_t*)(&KS[bb][(32 + l31) * 64 + ((gk ^ (l31 & 7)) << 3)]);
            st[0] = __builtin_amdgcn_mfma_f32_32x32x16_bf16(k0, qf[s], st[0], 0, 0, 0);
            st[1] = __builtin_amdgcn_mfma_f32_32x32x16_bf16(k1, qf[s], st[1], 0, 0, 0);
        }

        // ---- in-register online softmax (per-lane row q = lane&31) ----
        float tmax = st[0][0];
#pragma unroll
        for (int r = 1; r < 16; ++r) tmax = fmaxf(tmax, st[0][r]);
#pragma unroll
        for (int r = 0; r < 16; ++r) tmax = fmaxf(tmax, st[1][r]);
        tmax = fmaxf(tmax, __shfl_xor(tmax, 32));
        float mnew = fmaxf(mrun, tmax);
        float corr = __expf(mrun - mnew);
        mrun = mnew;
        float psum = 0.f;
#pragma unroll
        for (int t = 0; t < 2; ++t)
#pragma unroll
            for (int r = 0; r < 16; ++r) {
                float p = __expf(st[t][r] - mnew);
                st[t][r] = p;
                psum += p;
            }
        psum += __shfl_xor(psum, 32);
        lrun = lrun * corr + psum;
#pragma unroll
        for (int n = 0; n < 2; ++n)
#pragma unroll
            for (int r = 0; r < 16; ++r) ot[n][r] *= corr;

        // ---- pack P into PV B-fragments (bf16 pack + 8 shfl per tile) ----
        bf16x8_t pf[4];
#pragma unroll
        for (int t = 0; t < 2; ++t) {
            unsigned wv[8], ov[8];
#pragma unroll
            for (int j = 0; j < 8; ++j) wv[j] = pk2(st[t][2 * j], st[t][2 * j + 1]);
#pragma unroll
            for (int j = 0; j < 8; ++j) ov[j] = (unsigned)__shfl_xor((int)wv[j], 32);
#pragma unroll
            for (int sh = 0; sh < 2; ++sh) {
                int b = sh * 4;
                union { unsigned u[4]; bf16x8_t v; } u8;
                u8.u[0] = hi ? ov[b + 2] : wv[b + 0];
                u8.u[1] = hi ? ov[b + 3] : wv[b + 1];
                u8.u[2] = hi ? wv[b + 2] : ov[b + 0];
                u8.u[3] = hi ? wv[b + 3] : ov[b + 1];
                pf[t * 2 + sh] = u8.v;
            }
        }

        // ---- O^T += V^T . P  (2 d-tiles of 32 x K-dim 64 keys) ----
#pragma unroll
        for (int s = 0; s < 4; ++s) {
            int gk = s * 2 + hi;
            bf16x8_t v0 = *(const bf16x8_t*)(&VS[bb][l31 * 64 + ((gk ^ (l31 & 7)) << 3)]);
            bf16x8_t v1 = *(const bf16x8_t*)(&VS[bb][(32 + l31) * 64 + ((gk ^ (l31 & 7)) << 3)]);
            ot[0] = __builtin_amdgcn_mfma_f32_32x32x16_bf16(v0, pf[s], ot[0], 0, 0, 0);
            ot[1] = __builtin_amdgcn_mfma_f32_32x32x16_bf16(v1, pf[s], ot[1], 0, 0, 0);
        }
        __syncthreads();
    }

    // ---- epilogue: normalize, transpose via LDS, coalesced bf16 store ----
    float invl = 1.0f / lrun;
    ushort* Os = (ushort*)&KS[0][0];
    const int wbase = w * (64 * 33);
#pragma unroll
    for (int n = 0; n < 2; ++n)
#pragma unroll
        for (int r = 0; r < 16; ++r) {
            int d = n * 32 + (r & 3) + 8 * (r >> 2) + 4 * hi;
            Os[wbase + d * 33 + l31] = __bfloat16_as_ushort(__float2bfloat16(ot[n][r] * invl));
        }
    __syncthreads();
    {
        unsigned ow2[16];
#pragma unroll
        for (int j = 0; j < 16; ++j) {
            unsigned lo = Os[wbase + (hi * 32 + 2 * j) * 33 + l31];
            unsigned hh = Os[wbase + (hi * 32 + 2 * j + 1) * 33 + l31];
            ow2[j] = lo | (hh << 16);
        }
        uint4* gd = (uint4*)(attnb + (size_t)(t0 + l31) * D_MODEL + h * DH + hi * 32);
        gd[0] = make_uint4(ow2[0], ow2[1], ow2[2], ow2[3]);
        gd[1] = make_uint4(ow2[4], ow2[5], ow2[6], ow2[7]);
        gd[2] = make_uint4(ow2[8], ow2[9], ow2[10], ow2[11]);
        gd[3] = make_uint4(ow2[12], ow2[13], ow2[14], ow2[15]);
    }
}

// ---------------------------------------------------------------------------
extern "C" void kernel_launch(void* const* d_in, const int* in_sizes, int n_in,
                              void* d_out, int out_size, void* d_ws, size_t ws_size,
                              hipStream_t stream) {
    const float* hidden = (const float*)d_in[0];
    const float* Wqkv   = (const float*)d_in[1];
    const float* Wo     = (const float*)d_in[2];
    const int*   pos    = (const int*)d_in[3];

    char* ws = (char*)d_ws;
    float* qkv            = (float*)(ws);                       // 37,748,736 B
    __hip_bfloat16* Xb    = (__hip_bfloat16*)(ws + 37748736);   // 6,291,456
    __hip_bfloat16* Wqkvt = (__hip_bfloat16*)(ws + 44040192);   // 3,538,944
    __hip_bfloat16* Wot   = (__hip_bfloat16*)(ws + 47579136);   // 1,179,648
    __hip_bfloat16* Qb    = (__hip_bfloat16*)(ws + 48758784);   // 6,291,456
    __hip_bfloat16* Kb    = (__hip_bfloat16*)(ws + 55050240);   // 6,291,456
    __hip_bfloat16* Vtb   = (__hip_bfloat16*)(ws + 61341696);   // 6,291,456
    __hip_bfloat16* attnb = (__hip_bfloat16*)(ws + 67633152);   // 6,291,456
    float* out = (float*)d_out;

    // conversions
    conv_rows<<<(T_TOK * D_MODEL / 4 + 255) / 256, 256, 0, stream>>>(hidden, Xb, T_TOK * D_MODEL / 4);
    conv_transpose<<<dim3(QKV_LD / 64, D_MODEL / 64), 256, 0, stream>>>(Wqkv, Wqkvt, QKV_LD, D_MODEL);
    conv_transpose<<<dim3(D_MODEL / 64, D_MODEL / 64), 256, 0, stream>>>(Wo, Wot, D_MODEL, D_MODEL);

    // 1) qkv = X @ Wqkv (bf16 MFMA, fp32 out)
    gemm_bf16<<<dim3(QKV_LD / GBN, T_TOK / GBM), 256, 0, stream>>>(
        Xb, Wqkvt, qkv, T_TOK, QKV_LD, D_MODEL);

    // 2) RoPE -> Qb (scaled), Kb ; V -> Vtb (transposed)
    rope_bf16<<<(T_TOK * H_HEADS * 32 + 255) / 256, 256, 0, stream>>>(qkv, pos, Qb, Kb);
    v_transpose<<<dim3(H_HEADS, NSEG), 256, 0, stream>>>(qkv, Vtb);

    // 3) swapped-QK MFMA flash attention per 512-token segment
    attn_mfma<<<dim3(8, H_HEADS, NSEG), 128, 0, stream>>>(Qb, Kb, Vtb, attnb);

    // 4) out = attn @ Wo
    gemm_bf16<<<dim3(D_MODEL / GBN, T_TOK / GBM), 256, 0, stream>>>(
        attnb, Wot, out, T_TOK, D_MODEL, D_MODEL);
}

// Round 5
// 96.688 us; speedup vs baseline: 5.1172x; 1.2129x over previous
//
#include <hip/hip_runtime.h>
#include <hip/hip_bf16.h>
#include <math.h>

#define T_TOK 4096
#define D_MODEL 768
#define H_HEADS 12
#define DH 64
#define SEG 512
#define NSEG 8
#define QKV_LD 2304   // 3*D

typedef __bf16 bf16x8_t __attribute__((ext_vector_type(8)));
typedef float f32x4_t __attribute__((ext_vector_type(4)));
typedef float f32x16_t __attribute__((ext_vector_type(16)));

#define GBM 128
#define GBN 128
#define GBK 64

// stage one 128x64 A-tile + 128x64 B-tile into LDS buffer (8 loads/wave)
#define STAGE(As_, Bs_, Aptr_, Bptr_, K_, k0_)                                        \
    do {                                                                              \
        _Pragma("unroll")                                                             \
        for (int i_ = 0; i_ < 4; ++i_) {                                              \
            const int row_ = wid * 32 + i_ * 8;                                       \
            const __hip_bfloat16* ga_ = (Aptr_) + (size_t)(m0 + row_ + lr) * (K_) + (k0_) + lc; \
            __builtin_amdgcn_global_load_lds(                                         \
                (const __attribute__((address_space(1))) void*)ga_,                   \
                (__attribute__((address_space(3))) void*)((As_) + row_ * GBK), 16, 0, 0); \
            const __hip_bfloat16* gb_ = (Bptr_) + (size_t)(n0 + row_ + lr) * (K_) + (k0_) + lc; \
            __builtin_amdgcn_global_load_lds(                                         \
                (const __attribute__((address_space(1))) void*)gb_,                   \
                (__attribute__((address_space(3))) void*)((Bs_) + row_ * GBK), 16, 0, 0); \
        }                                                                             \
    } while (0)

// ---------------- plain bf16 MFMA GEMM (fp32 C out), 2-phase prefetch -------
__global__ __launch_bounds__(256) void gemm_bf16(const __hip_bfloat16* __restrict__ A,
                                                 const __hip_bfloat16* __restrict__ Bt,
                                                 float* __restrict__ C,
                                                 int M, int N, int K) {
    __shared__ __hip_bfloat16 As[2][GBM * GBK];
    __shared__ __hip_bfloat16 Bs[2][GBN * GBK];
    const int tid = threadIdx.x;
    const int lane = tid & 63;
    const int wid = tid >> 6;
    const int wr = wid >> 1, wc = wid & 1;
    const int m0 = blockIdx.y * GBM;
    const int n0 = blockIdx.x * GBN;

    f32x4_t acc[4][4];
#pragma unroll
    for (int i = 0; i < 4; ++i)
#pragma unroll
        for (int j = 0; j < 4; ++j) acc[i][j] = (f32x4_t){0.f, 0.f, 0.f, 0.f};

    const int lr = lane >> 3;
    const int lc = (lane & 7) * 8;
    const int fr = lane & 15;
    const int fk = (lane >> 4) * 8;

    const int NKT = K / GBK;
    STAGE(As[0], Bs[0], A, Bt, K, 0);
    for (int kt = 0; kt < NKT; ++kt) {
        const int cur = kt & 1;
        if (kt < NKT - 1) {
            STAGE(As[cur ^ 1], Bs[cur ^ 1], A, Bt, K, (kt + 1) * GBK);
            asm volatile("s_waitcnt vmcnt(8)" ::: "memory");
        } else {
            asm volatile("s_waitcnt vmcnt(0)" ::: "memory");
        }
        __builtin_amdgcn_s_barrier();
#pragma unroll
        for (int kk = 0; kk < 2; ++kk) {
            bf16x8_t af[4], bfr[4];
#pragma unroll
            for (int mi = 0; mi < 4; ++mi)
                af[mi] = *(const bf16x8_t*)(As[cur] + (wr * 64 + mi * 16 + fr) * GBK + kk * 32 + fk);
#pragma unroll
            for (int ni = 0; ni < 4; ++ni)
                bfr[ni] = *(const bf16x8_t*)(Bs[cur] + (wc * 64 + ni * 16 + fr) * GBK + kk * 32 + fk);
#pragma unroll
            for (int mi = 0; mi < 4; ++mi)
#pragma unroll
                for (int ni = 0; ni < 4; ++ni)
                    acc[mi][ni] = __builtin_amdgcn_mfma_f32_16x16x32_bf16(
                        af[mi], bfr[ni], acc[mi][ni], 0, 0, 0);
        }
        asm volatile("" ::: "memory");
        __builtin_amdgcn_s_barrier();
    }

    float* Cb = C + (size_t)(m0 + wr * 64) * N + n0 + wc * 64;
#pragma unroll
    for (int mi = 0; mi < 4; ++mi)
#pragma unroll
        for (int ni = 0; ni < 4; ++ni)
#pragma unroll
            for (int j = 0; j < 4; ++j) {
                int r = mi * 16 + (lane >> 4) * 4 + j;
                Cb[(size_t)r * N + ni * 16 + fr] = acc[mi][ni][j];
            }
}

// -------- QKV GEMM with fused RoPE + head-split + V-transpose epilogue ------
// A = Xb [4096][768] bf16, Bt = Wqkvt [2304][768] bf16.
// Wave's 64-col span = exactly one head of one of {q,k,v}.
// q: rope, x1/8 -> Qb[h][t][d] ; k: rope -> Kb[h][t][d] ; v -> Vtb[h][seg][d][key]
__global__ __launch_bounds__(256) void gemm_qkv_fused(const __hip_bfloat16* __restrict__ A,
                                                      const __hip_bfloat16* __restrict__ Bt,
                                                      const int* __restrict__ pos_ids,
                                                      __hip_bfloat16* __restrict__ Qb,
                                                      __hip_bfloat16* __restrict__ Kb,
                                                      __hip_bfloat16* __restrict__ Vtb) {
    __shared__ __hip_bfloat16 As[2][GBM * GBK];
    __shared__ __hip_bfloat16 Bs[2][GBN * GBK];
    const int tid = threadIdx.x;
    const int lane = tid & 63;
    const int wid = tid >> 6;
    const int wr = wid >> 1, wc = wid & 1;
    const int m0 = blockIdx.y * GBM;
    const int n0 = blockIdx.x * GBN;
    const int K = D_MODEL;

    f32x4_t acc[4][4];
#pragma unroll
    for (int i = 0; i < 4; ++i)
#pragma unroll
        for (int j = 0; j < 4; ++j) acc[i][j] = (f32x4_t){0.f, 0.f, 0.f, 0.f};

    const int lr = lane >> 3;
    const int lc = (lane & 7) * 8;
    const int fr = lane & 15;
    const int fk = (lane >> 4) * 8;
    const int l4 = lane >> 4;

    const int NKT = D_MODEL / GBK;   // 12
    STAGE(As[0], Bs[0], A, Bt, K, 0);
    for (int kt = 0; kt < NKT; ++kt) {
        const int cur = kt & 1;
        if (kt < NKT - 1) {
            STAGE(As[cur ^ 1], Bs[cur ^ 1], A, Bt, K, (kt + 1) * GBK);
            asm volatile("s_waitcnt vmcnt(8)" ::: "memory");
        } else {
            asm volatile("s_waitcnt vmcnt(0)" ::: "memory");
        }
        __builtin_amdgcn_s_barrier();
#pragma unroll
        for (int kk = 0; kk < 2; ++kk) {
            bf16x8_t af[4], bfr[4];
#pragma unroll
            for (int mi = 0; mi < 4; ++mi)
                af[mi] = *(const bf16x8_t*)(As[cur] + (wr * 64 + mi * 16 + fr) * GBK + kk * 32 + fk);
#pragma unroll
            for (int ni = 0; ni < 4; ++ni)
                bfr[ni] = *(const bf16x8_t*)(Bs[cur] + (wc * 64 + ni * 16 + fr) * GBK + kk * 32 + fk);
#pragma unroll
            for (int mi = 0; mi < 4; ++mi)
#pragma unroll
                for (int ni = 0; ni < 4; ++ni)
                    acc[mi][ni] = __builtin_amdgcn_mfma_f32_16x16x32_bf16(
                        af[mi], bfr[ni], acc[mi][ni], 0, 0, 0);
        }
        asm volatile("" ::: "memory");
        __builtin_amdgcn_s_barrier();
    }

    // ---- fused epilogue ----
    const int colbase = n0 + wc * 64;        // multiple of 64
    const int chunk = colbase >> 6;          // 0..35
    const int part = chunk / H_HEADS;        // 0=q 1=k 2=v
    const int h = chunk % H_HEADS;
    const int trow0 = m0 + wr * 64;

    if (part == 2) {
        // V: Vtb[(h*8+seg)*64 + d][key], pack 4 consecutive keys (j) per store
        const int seg = trow0 >> 9;
        const int key0 = (trow0 & 511) + l4 * 4;
        __hip_bfloat16* vdst = Vtb + ((size_t)(h * NSEG + seg) * DH) * SEG;
#pragma unroll
        for (int mi = 0; mi < 4; ++mi)
#pragma unroll
            for (int ni = 0; ni < 4; ++ni) {
                int d = ni * 16 + fr;
                union { __hip_bfloat16 h2[4]; ushort4 u; } o;
#pragma unroll
                for (int j = 0; j < 4; ++j) o.h2[j] = __float2bfloat16(acc[mi][ni][j]);
                *(ushort4*)(vdst + (size_t)d * SEG + key0 + mi * 16) = o.u;
            }
    } else {
        __hip_bfloat16* dst = (part == 0) ? Qb : Kb;
        const float scale = (part == 0) ? 0.125f : 1.0f;
        // per-lane inv_freq for i0 = fr, i1 = 16+fr (wave-uniform over rows)
        const float if0 = powf(160000.0f, -(float)fr / 32.0f);
        const float if1 = powf(160000.0f, -(float)(16 + fr) / 32.0f);
#pragma unroll
        for (int mi = 0; mi < 4; ++mi)
#pragma unroll
            for (int j = 0; j < 4; ++j) {
                int t = trow0 + mi * 16 + l4 * 4 + j;
                float pos = (float)pos_ids[t];
                float s0, c0, s1, c1;
                sincosf(pos * if0, &s0, &c0);
                sincosf(pos * if1, &s1, &c1);
                __hip_bfloat16* op = dst + ((size_t)h * T_TOK + t) * DH;
                float x1, x2;
                x1 = acc[mi][0][j]; x2 = acc[mi][2][j];          // d = fr, fr+32
                op[fr]      = __float2bfloat16((x1 * c0 - x2 * s0) * scale);
                op[fr + 32] = __float2bfloat16((x2 * c0 + x1 * s0) * scale);
                x1 = acc[mi][1][j]; x2 = acc[mi][3][j];          // d = 16+fr, 48+fr
                op[16 + fr] = __float2bfloat16((x1 * c1 - x2 * s1) * scale);
                op[48 + fr] = __float2bfloat16((x2 * c1 + x1 * s1) * scale);
            }
    }
}

// ---------------- fp32 -> bf16 rows -----------------------------------------
__global__ __launch_bounds__(256) void conv_rows(const float* __restrict__ in,
                                                 __hip_bfloat16* __restrict__ out,
                                                 int total4) {
    int i = blockIdx.x * 256 + threadIdx.x;
    if (i >= total4) return;
    float4 v = ((const float4*)in)[i];
    union { __hip_bfloat16 h[4]; ushort4 u; } o;
    o.h[0] = __float2bfloat16(v.x); o.h[1] = __float2bfloat16(v.y);
    o.h[2] = __float2bfloat16(v.z); o.h[3] = __float2bfloat16(v.w);
    ((ushort4*)out)[i] = o.u;
}

// ---------------- fp32 [K][N] -> bf16 [N][K] (transpose-convert) ------------
__global__ __launch_bounds__(256) void conv_transpose(const float* __restrict__ in,
                                                      __hip_bfloat16* __restrict__ out,
                                                      int N, int K) {
    __shared__ float tile[64][65];
    const int k0 = blockIdx.y * 64;
    const int n0 = blockIdx.x * 64;
    const int tid = threadIdx.x;
    const int rr = tid >> 4;
    const int cc = (tid & 15) * 4;
#pragma unroll
    for (int i = 0; i < 4; ++i) {
        int r = i * 16 + rr;
        float4 v = *(const float4*)(in + (size_t)(k0 + r) * N + n0 + cc);
        tile[r][cc] = v.x; tile[r][cc + 1] = v.y; tile[r][cc + 2] = v.z; tile[r][cc + 3] = v.w;
    }
    __syncthreads();
#pragma unroll
    for (int i = 0; i < 4; ++i) {
        int n = i * 16 + rr;
        union { __hip_bfloat16 h[4]; ushort4 u; } o;
        o.h[0] = __float2bfloat16(tile[cc + 0][n]);
        o.h[1] = __float2bfloat16(tile[cc + 1][n]);
        o.h[2] = __float2bfloat16(tile[cc + 2][n]);
        o.h[3] = __float2bfloat16(tile[cc + 3][n]);
        *(ushort4*)(out + (size_t)(n0 + n) * K + k0 + cc) = o.u;
    }
}

// ---------------- swapped-QK in-register-softmax flash attention ------------
__device__ __forceinline__ unsigned pk2(float a, float b) {
    unsigned ua = (unsigned)__bfloat16_as_ushort(__float2bfloat16(a));
    unsigned ub = (unsigned)__bfloat16_as_ushort(__float2bfloat16(b));
    return ua | (ub << 16);
}

__global__ __launch_bounds__(128) void attn_mfma(const __hip_bfloat16* __restrict__ Qb,
                                                 const __hip_bfloat16* __restrict__ Kb,
                                                 const __hip_bfloat16* __restrict__ Vtb,
                                                 __hip_bfloat16* __restrict__ attnb) {
    __shared__ __hip_bfloat16 KS[2][64 * 64];
    __shared__ __hip_bfloat16 VS[2][64 * 64];

    const int tid = threadIdx.x;
    const int lane = tid & 63;
    const int w = tid >> 6;
    const int hi = lane >> 5;
    const int l31 = lane & 31;
    const int qt = blockIdx.x, h = blockIdx.y, seg = blockIdx.z;
    const int t0 = seg * SEG + qt * 64 + w * 32;

    const __hip_bfloat16* kb = Kb + ((size_t)h * T_TOK + seg * SEG) * DH;
    const __hip_bfloat16* vb = Vtb + (size_t)(h * NSEG + seg) * DH * SEG;

    bf16x8_t qf[4];
    {
        const __hip_bfloat16* qp = Qb + ((size_t)h * T_TOK + t0 + l31) * DH + hi * 8;
#pragma unroll
        for (int s = 0; s < 4; ++s) qf[s] = *(const bf16x8_t*)(qp + s * 16);
    }

    const int gr = lane >> 3;
    const int gc = lane & 7;

#pragma unroll
    for (int i = 0; i < 4; ++i) {
        int G = i * 128 + w * 64;
        int rk = (G >> 3) + gr;
        const __hip_bfloat16* sk = kb + (size_t)rk * DH + ((gc ^ (rk & 7)) << 3);
        __builtin_amdgcn_global_load_lds(
            (const __attribute__((address_space(1))) void*)sk,
            (__attribute__((address_space(3))) void*)(&KS[0][G * 8]), 16, 0, 0);
        const __hip_bfloat16* sv = vb + (size_t)rk * SEG + ((gc ^ (rk & 7)) << 3);
        __builtin_amdgcn_global_load_lds(
            (const __attribute__((address_space(1))) void*)sv,
            (__attribute__((address_space(3))) void*)(&VS[0][G * 8]), 16, 0, 0);
    }
    __syncthreads();

    f32x16_t ot[2];
#pragma unroll
    for (int n = 0; n < 2; ++n)
#pragma unroll
        for (int r = 0; r < 16; ++r) ot[n][r] = 0.f;
    float mrun = -3.0e38f, lrun = 0.f;

    for (int kv = 0; kv < 8; ++kv) {
        const int bb = kv & 1;
        if (kv < 7) {
#pragma unroll
            for (int i = 0; i < 4; ++i) {
                int G = i * 128 + w * 64;
                int rk = (G >> 3) + gr;
                const __hip_bfloat16* sk = kb + (size_t)((kv + 1) * 64 + rk) * DH + ((gc ^ (rk & 7)) << 3);
                __builtin_amdgcn_global_load_lds(
                    (const __attribute__((address_space(1))) void*)sk,
                    (__attribute__((address_space(3))) void*)(&KS[bb ^ 1][G * 8]), 16, 0, 0);
                const __hip_bfloat16* sv = vb + (size_t)rk * SEG + (kv + 1) * 64 + ((gc ^ (rk & 7)) << 3);
                __builtin_amdgcn_global_load_lds(
                    (const __attribute__((address_space(1))) void*)sv,
                    (__attribute__((address_space(3))) void*)(&VS[bb ^ 1][G * 8]), 16, 0, 0);
            }
        }

        f32x16_t st[2];
#pragma unroll
        for (int t = 0; t < 2; ++t)
#pragma unroll
            for (int r = 0; r < 16; ++r) st[t][r] = 0.f;
#pragma unroll
        for (int s = 0; s < 4; ++s) {
            int gk = s * 2 + hi;
            bf16x8_t k0 = *(const bf16x8_t*)(&KS[bb][l31 * 64 + ((gk ^ (l31 & 7)) << 3)]);
            bf16x8_t k1 = *(const bf16x8_t*)(&KS[bb][(32 + l31) * 64 + ((gk ^ (l31 & 7)) << 3)]);
            st[0] = __builtin_amdgcn_mfma_f32_32x32x16_bf16(k0, qf[s], st[0], 0, 0, 0);
            st[1] = __builtin_amdgcn_mfma_f32_32x32x16_bf16(k1, qf[s], st[1], 0, 0, 0);
        }

        float tmax = st[0][0];
#pragma unroll
        for (int r = 1; r < 16; ++r) tmax = fmaxf(tmax, st[0][r]);
#pragma unroll
        for (int r = 0; r < 16; ++r) tmax = fmaxf(tmax, st[1][r]);
        tmax = fmaxf(tmax, __shfl_xor(tmax, 32));
        float mnew = fmaxf(mrun, tmax);
        float corr = __expf(mrun - mnew);
        mrun = mnew;
        float psum = 0.f;
#pragma unroll
        for (int t = 0; t < 2; ++t)
#pragma unroll
            for (int r = 0; r < 16; ++r) {
                float p = __expf(st[t][r] - mnew);
                st[t][r] = p;
                psum += p;
            }
        psum += __shfl_xor(psum, 32);
        lrun = lrun * corr + psum;
#pragma unroll
        for (int n = 0; n < 2; ++n)
#pragma unroll
            for (int r = 0; r < 16; ++r) ot[n][r] *= corr;

        bf16x8_t pf[4];
#pragma unroll
        for (int t = 0; t < 2; ++t) {
            unsigned wv[8], ov[8];
#pragma unroll
            for (int j = 0; j < 8; ++j) wv[j] = pk2(st[t][2 * j], st[t][2 * j + 1]);
#pragma unroll
            for (int j = 0; j < 8; ++j) ov[j] = (unsigned)__shfl_xor((int)wv[j], 32);
#pragma unroll
            for (int sh = 0; sh < 2; ++sh) {
                int b = sh * 4;
                union { unsigned u[4]; bf16x8_t v; } u8;
                u8.u[0] = hi ? ov[b + 2] : wv[b + 0];
                u8.u[1] = hi ? ov[b + 3] : wv[b + 1];
                u8.u[2] = hi ? wv[b + 2] : ov[b + 0];
                u8.u[3] = hi ? wv[b + 3] : ov[b + 1];
                pf[t * 2 + sh] = u8.v;
            }
        }

#pragma unroll
        for (int s = 0; s < 4; ++s) {
            int gk = s * 2 + hi;
            bf16x8_t v0 = *(const bf16x8_t*)(&VS[bb][l31 * 64 + ((gk ^ (l31 & 7)) << 3)]);
            bf16x8_t v1 = *(const bf16x8_t*)(&VS[bb][(32 + l31) * 64 + ((gk ^ (l31 & 7)) << 3)]);
            ot[0] = __builtin_amdgcn_mfma_f32_32x32x16_bf16(v0, pf[s], ot[0], 0, 0, 0);
            ot[1] = __builtin_amdgcn_mfma_f32_32x32x16_bf16(v1, pf[s], ot[1], 0, 0, 0);
        }
        __syncthreads();
    }

    float invl = 1.0f / lrun;
    ushort* Os = (ushort*)&KS[0][0];
    const int wbase = w * (64 * 33);
#pragma unroll
    for (int n = 0; n < 2; ++n)
#pragma unroll
        for (int r = 0; r < 16; ++r) {
            int d = n * 32 + (r & 3) + 8 * (r >> 2) + 4 * hi;
            Os[wbase + d * 33 + l31] = __bfloat16_as_ushort(__float2bfloat16(ot[n][r] * invl));
        }
    __syncthreads();
    {
        unsigned ow2[16];
#pragma unroll
        for (int j = 0; j < 16; ++j) {
            unsigned lo = Os[wbase + (hi * 32 + 2 * j) * 33 + l31];
            unsigned hh = Os[wbase + (hi * 32 + 2 * j + 1) * 33 + l31];
            ow2[j] = lo | (hh << 16);
        }
        uint4* gd = (uint4*)(attnb + (size_t)(t0 + l31) * D_MODEL + h * DH + hi * 32);
        gd[0] = make_uint4(ow2[0], ow2[1], ow2[2], ow2[3]);
        gd[1] = make_uint4(ow2[4], ow2[5], ow2[6], ow2[7]);
        gd[2] = make_uint4(ow2[8], ow2[9], ow2[10], ow2[11]);
        gd[3] = make_uint4(ow2[12], ow2[13], ow2[14], ow2[15]);
    }
}

// ---------------------------------------------------------------------------
extern "C" void kernel_launch(void* const* d_in, const int* in_sizes, int n_in,
                              void* d_out, int out_size, void* d_ws, size_t ws_size,
                              hipStream_t stream) {
    const float* hidden = (const float*)d_in[0];
    const float* Wqkv   = (const float*)d_in[1];
    const float* Wo     = (const float*)d_in[2];
    const int*   pos    = (const int*)d_in[3];

    char* ws = (char*)d_ws;
    __hip_bfloat16* Xb    = (__hip_bfloat16*)(ws);              // 6,291,456
    __hip_bfloat16* Wqkvt = (__hip_bfloat16*)(ws + 6291456);    // 3,538,944
    __hip_bfloat16* Wot   = (__hip_bfloat16*)(ws + 9830400);    // 1,179,648
    __hip_bfloat16* Qb    = (__hip_bfloat16*)(ws + 11010048);   // 6,291,456
    __hip_bfloat16* Kb    = (__hip_bfloat16*)(ws + 17301504);   // 6,291,456
    __hip_bfloat16* Vtb   = (__hip_bfloat16*)(ws + 23592960);   // 6,291,456
    __hip_bfloat16* attnb = (__hip_bfloat16*)(ws + 29884416);   // 6,291,456
    float* out = (float*)d_out;

    // conversions
    conv_rows<<<(T_TOK * D_MODEL / 4 + 255) / 256, 256, 0, stream>>>(hidden, Xb, T_TOK * D_MODEL / 4);
    conv_transpose<<<dim3(QKV_LD / 64, D_MODEL / 64), 256, 0, stream>>>(Wqkv, Wqkvt, QKV_LD, D_MODEL);
    conv_transpose<<<dim3(D_MODEL / 64, D_MODEL / 64), 256, 0, stream>>>(Wo, Wot, D_MODEL, D_MODEL);

    // 1) fused QKV GEMM + RoPE + head-split + V-transpose
    gemm_qkv_fused<<<dim3(QKV_LD / GBN, T_TOK / GBM), 256, 0, stream>>>(
        Xb, Wqkvt, pos, Qb, Kb, Vtb);

    // 2) swapped-QK MFMA flash attention per 512-token segment
    attn_mfma<<<dim3(8, H_HEADS, NSEG), 128, 0, stream>>>(Qb, Kb, Vtb, attnb);

    // 3) out = attn @ Wo
    gemm_bf16<<<dim3(D_MODEL / GBN, T_TOK / GBM), 256, 0, stream>>>(
        attnb, Wot, out, T_TOK, D_MODEL, D_MODEL);
}

// Round 7
// 93.082 us; speedup vs baseline: 5.3154x; 1.0387x over previous
//
#include <hip/hip_runtime.h>
#include <hip/hip_bf16.h>
#include <math.h>

#define T_TOK 4096
#define D_MODEL 768
#define H_HEADS 12
#define DH 64
#define SEG 512
#define NSEG 8
#define QKV_LD 2304   // 3*D

typedef __bf16 bf16x8_t __attribute__((ext_vector_type(8)));
typedef float f32x4_t __attribute__((ext_vector_type(4)));
typedef float f32x16_t __attribute__((ext_vector_type(16)));

#define GBK 64

// compile-time-fenced workgroup barrier: sched_barrier(0) pins ALL instruction
// motion across the raw s_barrier (rule #18: "memory" clobbers do not order
// MFMA/hoisted LDS ops; raw s_barrier is not a compiler fence).
#define FENCED_BARRIER()                         \
    do {                                         \
        __builtin_amdgcn_sched_barrier(0);       \
        __builtin_amdgcn_s_barrier();            \
        __builtin_amdgcn_sched_barrier(0);       \
    } while (0)

// ---------------------------------------------------------------------------
// prep: fp32->bf16 convert of X (rows) + transpose-convert of Wqkv, Wo
// grid: [0,3072) conv X ; [3072,3504) Wqkv^T (36x12) ; [3504,3648) Wo^T (12x12)
// ---------------------------------------------------------------------------
__device__ __forceinline__ void tconv_body(const float* __restrict__ in,
                                           __hip_bfloat16* __restrict__ out,
                                           int N, int K, int bx, int by, int tid,
                                           float (*tile)[65]) {
    const int k0 = by * 64;
    const int n0 = bx * 64;
    const int rr = tid >> 4;
    const int cc = (tid & 15) * 4;
#pragma unroll
    for (int i = 0; i < 4; ++i) {
        int r = i * 16 + rr;
        float4 v = *(const float4*)(in + (size_t)(k0 + r) * N + n0 + cc);
        tile[r][cc] = v.x; tile[r][cc + 1] = v.y; tile[r][cc + 2] = v.z; tile[r][cc + 3] = v.w;
    }
    __syncthreads();
#pragma unroll
    for (int i = 0; i < 4; ++i) {
        int n = i * 16 + rr;
        union { __hip_bfloat16 h[4]; ushort4 u; } o;
        o.h[0] = __float2bfloat16(tile[cc + 0][n]);
        o.h[1] = __float2bfloat16(tile[cc + 1][n]);
        o.h[2] = __float2bfloat16(tile[cc + 2][n]);
        o.h[3] = __float2bfloat16(tile[cc + 3][n]);
        *(ushort4*)(out + (size_t)(n0 + n) * K + k0 + cc) = o.u;
    }
}

__global__ __launch_bounds__(256) void prep_inputs(const float* __restrict__ hidden,
                                                   const float* __restrict__ Wqkv,
                                                   const float* __restrict__ Wo,
                                                   __hip_bfloat16* __restrict__ Xb,
                                                   __hip_bfloat16* __restrict__ Wqkvt,
                                                   __hip_bfloat16* __restrict__ Wot) {
    __shared__ float tile[64][65];
    const int b = blockIdx.x;
    const int tid = threadIdx.x;
    if (b < 3072) {
        int i = b * 256 + tid;   // T*D/4 = 786432 exactly
        float4 v = ((const float4*)hidden)[i];
        union { __hip_bfloat16 h[4]; ushort4 u; } o;
        o.h[0] = __float2bfloat16(v.x); o.h[1] = __float2bfloat16(v.y);
        o.h[2] = __float2bfloat16(v.z); o.h[3] = __float2bfloat16(v.w);
        ((ushort4*)Xb)[i] = o.u;
    } else if (b < 3504) {
        int lb = b - 3072;                // 36 x 12
        tconv_body(Wqkv, Wqkvt, QKV_LD, D_MODEL, lb % 36, lb / 36, tid, tile);
    } else {
        int lb = b - 3504;                // 12 x 12
        tconv_body(Wo, Wot, D_MODEL, D_MODEL, lb % 12, lb / 12, tid, tile);
    }
}

// ---------------------------------------------------------------------------
// QKV GEMM (512 thr, 8 waves, 128x128 tile) + fused RoPE/head-split/V-transpose
// A = Xb [4096][768], Bt = Wqkvt [2304][768]. Wave = 32 rows x 64 cols = 1 head span.
// ---------------------------------------------------------------------------
__global__ __launch_bounds__(512) void gemm_qkv_fused(const __hip_bfloat16* __restrict__ A,
                                                      const __hip_bfloat16* __restrict__ Bt,
                                                      const int* __restrict__ pos_ids,
                                                      __hip_bfloat16* __restrict__ Qb,
                                                      __hip_bfloat16* __restrict__ Kb,
                                                      __hip_bfloat16* __restrict__ Vtb) {
    __shared__ __hip_bfloat16 As[2][128 * GBK];
    __shared__ __hip_bfloat16 Bs[2][128 * GBK];
    const int tid = threadIdx.x;
    const int lane = tid & 63;
    const int wid = tid >> 6;          // 0..7
    const int wr = wid >> 1;           // 0..3
    const int wc = wid & 1;            // 0..1
    const int m0 = blockIdx.y * 128;
    const int n0 = blockIdx.x * 128;
    const int K = D_MODEL;

    f32x4_t acc[2][4];
#pragma unroll
    for (int i = 0; i < 2; ++i)
#pragma unroll
        for (int j = 0; j < 4; ++j) acc[i][j] = (f32x4_t){0.f, 0.f, 0.f, 0.f};

    const int lr = lane >> 3;
    const int lc = (lane & 7) * 8;
    const int fr = lane & 15;
    const int fk = (lane >> 4) * 8;
    const int l4 = lane >> 4;

#define STAGE_Q(buf_, k0_)                                                            \
    do {                                                                              \
        _Pragma("unroll")                                                             \
        for (int i_ = 0; i_ < 2; ++i_) {                                              \
            const int row_ = i_ * 64 + wid * 8;                                       \
            const __hip_bfloat16* ga_ = A + (size_t)(m0 + row_ + lr) * K + (k0_) + lc; \
            __builtin_amdgcn_global_load_lds(                                         \
                (const __attribute__((address_space(1))) void*)ga_,                   \
                (__attribute__((address_space(3))) void*)(As[buf_] + row_ * GBK), 16, 0, 0); \
            const __hip_bfloat16* gb_ = Bt + (size_t)(n0 + row_ + lr) * K + (k0_) + lc; \
            __builtin_amdgcn_global_load_lds(                                         \
                (const __attribute__((address_space(1))) void*)gb_,                   \
                (__attribute__((address_space(3))) void*)(Bs[buf_] + row_ * GBK), 16, 0, 0); \
        }                                                                             \
    } while (0)

    const int NKT = K / GBK;   // 12
    STAGE_Q(0, 0);
    for (int kt = 0; kt < NKT; ++kt) {
        const int cur = kt & 1;
        if (kt < NKT - 1) {
            STAGE_Q(cur ^ 1, (kt + 1) * GBK);
            asm volatile("s_waitcnt vmcnt(4)" ::: "memory");
        } else {
            asm volatile("s_waitcnt vmcnt(0)" ::: "memory");
        }
        FENCED_BARRIER();
#pragma unroll
        for (int kk = 0; kk < 2; ++kk) {
            bf16x8_t af[2], bfr[4];
#pragma unroll
            for (int mi = 0; mi < 2; ++mi)
                af[mi] = *(const bf16x8_t*)(As[cur] + (wr * 32 + mi * 16 + fr) * GBK + kk * 32 + fk);
#pragma unroll
            for (int ni = 0; ni < 4; ++ni)
                bfr[ni] = *(const bf16x8_t*)(Bs[cur] + (wc * 64 + ni * 16 + fr) * GBK + kk * 32 + fk);
#pragma unroll
            for (int mi = 0; mi < 2; ++mi)
#pragma unroll
                for (int ni = 0; ni < 4; ++ni)
                    acc[mi][ni] = __builtin_amdgcn_mfma_f32_16x16x32_bf16(
                        af[mi], bfr[ni], acc[mi][ni], 0, 0, 0);
        }
        asm volatile("" ::: "memory");
        FENCED_BARRIER();
    }
#undef STAGE_Q

    // ---- fused epilogue ----
    const int colbase = n0 + wc * 64;        // multiple of 64
    const int chunk = colbase >> 6;          // 0..35
    const int part = chunk / H_HEADS;        // 0=q 1=k 2=v
    const int h = chunk % H_HEADS;
    const int trow0 = m0 + wr * 32;

    if (part == 2) {
        const int seg = trow0 >> 9;
        const int key0 = (trow0 & 511) + l4 * 4;
        __hip_bfloat16* vdst = Vtb + ((size_t)(h * NSEG + seg) * DH) * SEG;
#pragma unroll
        for (int mi = 0; mi < 2; ++mi)
#pragma unroll
            for (int ni = 0; ni < 4; ++ni) {
                int d = ni * 16 + fr;
                union { __hip_bfloat16 h2[4]; ushort4 u; } o;
#pragma unroll
                for (int j = 0; j < 4; ++j) o.h2[j] = __float2bfloat16(acc[mi][ni][j]);
                *(ushort4*)(vdst + (size_t)d * SEG + key0 + mi * 16) = o.u;
            }
    } else {
        __hip_bfloat16* dst = (part == 0) ? Qb : Kb;
        const float scale = (part == 0) ? 0.125f : 1.0f;
        const float if0 = powf(160000.0f, -(float)fr / 32.0f);
        const float if1 = powf(160000.0f, -(float)(16 + fr) / 32.0f);
#pragma unroll
        for (int mi = 0; mi < 2; ++mi)
#pragma unroll
            for (int j = 0; j < 4; ++j) {
                int t = trow0 + mi * 16 + l4 * 4 + j;
                float pos = (float)pos_ids[t];
                float s0, c0, s1, c1;
                sincosf(pos * if0, &s0, &c0);
                sincosf(pos * if1, &s1, &c1);
                __hip_bfloat16* op = dst + ((size_t)h * T_TOK + t) * DH;
                float x1, x2;
                x1 = acc[mi][0][j]; x2 = acc[mi][2][j];
                op[fr]      = __float2bfloat16((x1 * c0 - x2 * s0) * scale);
                op[fr + 32] = __float2bfloat16((x2 * c0 + x1 * s0) * scale);
                x1 = acc[mi][1][j]; x2 = acc[mi][3][j];
                op[16 + fr] = __float2bfloat16((x1 * c1 - x2 * s1) * scale);
                op[48 + fr] = __float2bfloat16((x2 * c1 + x1 * s1) * scale);
            }
    }
}

// ---------------------------------------------------------------------------
// Wo GEMM: 64x64 tile, 256 thr, grid 12x64 = 768 blocks (fixes CU starvation)
// C[4096][768] fp32 = attnb[4096][768] @ Wot[768][768]^T
// ---------------------------------------------------------------------------
__global__ __launch_bounds__(256) void gemm_wo64(const __hip_bfloat16* __restrict__ A,
                                                 const __hip_bfloat16* __restrict__ Bt,
                                                 float* __restrict__ C) {
    __shared__ __hip_bfloat16 As[2][64 * GBK];
    __shared__ __hip_bfloat16 Bs[2][64 * GBK];
    const int tid = threadIdx.x;
    const int lane = tid & 63;
    const int wid = tid >> 6;          // 0..3
    const int wr = wid >> 1, wc = wid & 1;
    const int m0 = blockIdx.y * 64;
    const int n0 = blockIdx.x * 64;
    const int K = D_MODEL;
    const int N = D_MODEL;

    f32x4_t acc[2][2];
#pragma unroll
    for (int i = 0; i < 2; ++i)
#pragma unroll
        for (int j = 0; j < 2; ++j) acc[i][j] = (f32x4_t){0.f, 0.f, 0.f, 0.f};

    const int lr = lane >> 3;
    const int lc = (lane & 7) * 8;
    const int fr = lane & 15;
    const int fk = (lane >> 4) * 8;

#define STAGE_W(buf_, k0_)                                                            \
    do {                                                                              \
        _Pragma("unroll")                                                             \
        for (int i_ = 0; i_ < 2; ++i_) {                                              \
            const int row_ = i_ * 32 + wid * 8;                                       \
            const __hip_bfloat16* ga_ = A + (size_t)(m0 + row_ + lr) * K + (k0_) + lc; \
            __builtin_amdgcn_global_load_lds(                                         \
                (const __attribute__((address_space(1))) void*)ga_,                   \
                (__attribute__((address_space(3))) void*)(As[buf_] + row_ * GBK), 16, 0, 0); \
            const __hip_bfloat16* gb_ = Bt + (size_t)(n0 + row_ + lr) * K + (k0_) + lc; \
            __builtin_amdgcn_global_load_lds(                                         \
                (const __attribute__((address_space(1))) void*)gb_,                   \
                (__attribute__((address_space(3))) void*)(Bs[buf_] + row_ * GBK), 16, 0, 0); \
        }                                                                             \
    } while (0)

    const int NKT = K / GBK;   // 12
    STAGE_W(0, 0);
    for (int kt = 0; kt < NKT; ++kt) {
        const int cur = kt & 1;
        if (kt < NKT - 1) {
            STAGE_W(cur ^ 1, (kt + 1) * GBK);
            asm volatile("s_waitcnt vmcnt(4)" ::: "memory");
        } else {
            asm volatile("s_waitcnt vmcnt(0)" ::: "memory");
        }
        FENCED_BARRIER();
#pragma unroll
        for (int kk = 0; kk < 2; ++kk) {
            bf16x8_t af[2], bfr[2];
#pragma unroll
            for (int mi = 0; mi < 2; ++mi)
                af[mi] = *(const bf16x8_t*)(As[cur] + (wr * 32 + mi * 16 + fr) * GBK + kk * 32 + fk);
#pragma unroll
            for (int ni = 0; ni < 2; ++ni)
                bfr[ni] = *(const bf16x8_t*)(Bs[cur] + (wc * 32 + ni * 16 + fr) * GBK + kk * 32 + fk);
#pragma unroll
            for (int mi = 0; mi < 2; ++mi)
#pragma unroll
                for (int ni = 0; ni < 2; ++ni)
                    acc[mi][ni] = __builtin_amdgcn_mfma_f32_16x16x32_bf16(
                        af[mi], bfr[ni], acc[mi][ni], 0, 0, 0);
        }
        asm volatile("" ::: "memory");
        FENCED_BARRIER();
    }
#undef STAGE_W

    float* Cb = C + (size_t)(m0 + wr * 32) * N + n0 + wc * 32;
#pragma unroll
    for (int mi = 0; mi < 2; ++mi)
#pragma unroll
        for (int ni = 0; ni < 2; ++ni)
#pragma unroll
            for (int j = 0; j < 4; ++j) {
                int r = mi * 16 + (lane >> 4) * 4 + j;
                Cb[(size_t)r * N + ni * 16 + fr] = acc[mi][ni][j];
            }
}

// ---------------- swapped-QK in-register-softmax flash attention ------------
__device__ __forceinline__ unsigned pk2(float a, float b) {
    unsigned ua = (unsigned)__bfloat16_as_ushort(__float2bfloat16(a));
    unsigned ub = (unsigned)__bfloat16_as_ushort(__float2bfloat16(b));
    return ua | (ub << 16);
}

__global__ __launch_bounds__(128) void attn_mfma(const __hip_bfloat16* __restrict__ Qb,
                                                 const __hip_bfloat16* __restrict__ Kb,
                                                 const __hip_bfloat16* __restrict__ Vtb,
                                                 __hip_bfloat16* __restrict__ attnb) {
    __shared__ __hip_bfloat16 KS[2][64 * 64];
    __shared__ __hip_bfloat16 VS[2][64 * 64];

    const int tid = threadIdx.x;
    const int lane = tid & 63;
    const int w = tid >> 6;
    const int hi = lane >> 5;
    const int l31 = lane & 31;
    const int qt = blockIdx.x, h = blockIdx.y, seg = blockIdx.z;
    const int t0 = seg * SEG + qt * 64 + w * 32;

    const __hip_bfloat16* kb = Kb + ((size_t)h * T_TOK + seg * SEG) * DH;
    const __hip_bfloat16* vb = Vtb + (size_t)(h * NSEG + seg) * DH * SEG;

    bf16x8_t qf[4];
    {
        const __hip_bfloat16* qp = Qb + ((size_t)h * T_TOK + t0 + l31) * DH + hi * 8;
#pragma unroll
        for (int s = 0; s < 4; ++s) qf[s] = *(const bf16x8_t*)(qp + s * 16);
    }

    const int gr = lane >> 3;
    const int gc = lane & 7;

#pragma unroll
    for (int i = 0; i < 4; ++i) {
        int G = i * 128 + w * 64;
        int rk = (G >> 3) + gr;
        const __hip_bfloat16* sk = kb + (size_t)rk * DH + ((gc ^ (rk & 7)) << 3);
        __builtin_amdgcn_global_load_lds(
            (const __attribute__((address_space(1))) void*)sk,
            (__attribute__((address_space(3))) void*)(&KS[0][G * 8]), 16, 0, 0);
        const __hip_bfloat16* sv = vb + (size_t)rk * SEG + ((gc ^ (rk & 7)) << 3);
        __builtin_amdgcn_global_load_lds(
            (const __attribute__((address_space(1))) void*)sv,
            (__attribute__((address_space(3))) void*)(&VS[0][G * 8]), 16, 0, 0);
    }
    __syncthreads();

    f32x16_t ot[2];
#pragma unroll
    for (int n = 0; n < 2; ++n)
#pragma unroll
        for (int r = 0; r < 16; ++r) ot[n][r] = 0.f;
    float mrun = -3.0e38f, lrun = 0.f;

    for (int kv = 0; kv < 8; ++kv) {
        const int bb = kv & 1;
        if (kv < 7) {
#pragma unroll
            for (int i = 0; i < 4; ++i) {
                int G = i * 128 + w * 64;
                int rk = (G >> 3) + gr;
                const __hip_bfloat16* sk = kb + (size_t)((kv + 1) * 64 + rk) * DH + ((gc ^ (rk & 7)) << 3);
                __builtin_amdgcn_global_load_lds(
                    (const __attribute__((address_space(1))) void*)sk,
                    (__attribute__((address_space(3))) void*)(&KS[bb ^ 1][G * 8]), 16, 0, 0);
                const __hip_bfloat16* sv = vb + (size_t)rk * SEG + (kv + 1) * 64 + ((gc ^ (rk & 7)) << 3);
                __builtin_amdgcn_global_load_lds(
                    (const __attribute__((address_space(1))) void*)sv,
                    (__attribute__((address_space(3))) void*)(&VS[bb ^ 1][G * 8]), 16, 0, 0);
            }
        }

        f32x16_t st[2];
#pragma unroll
        for (int t = 0; t < 2; ++t)
#pragma unroll
            for (int r = 0; r < 16; ++r) st[t][r] = 0.f;
#pragma unroll
        for (int s = 0; s < 4; ++s) {
            int gk = s * 2 + hi;
            bf16x8_t k0 = *(const bf16x8_t*)(&KS[bb][l31 * 64 + ((gk ^ (l31 & 7)) << 3)]);
            bf16x8_t k1 = *(const bf16x8_t*)(&KS[bb][(32 + l31) * 64 + ((gk ^ (l31 & 7)) << 3)]);
            st[0] = __builtin_amdgcn_mfma_f32_32x32x16_bf16(k0, qf[s], st[0], 0, 0, 0);
            st[1] = __builtin_amdgcn_mfma_f32_32x32x16_bf16(k1, qf[s], st[1], 0, 0, 0);
        }

        float tmax = st[0][0];
#pragma unroll
        for (int r = 1; r < 16; ++r) tmax = fmaxf(tmax, st[0][r]);
#pragma unroll
        for (int r = 0; r < 16; ++r) tmax = fmaxf(tmax, st[1][r]);
        tmax = fmaxf(tmax, __shfl_xor(tmax, 32));
        float mnew = fmaxf(mrun, tmax);
        float corr = __expf(mrun - mnew);
        mrun = mnew;
        float psum = 0.f;
#pragma unroll
        for (int t = 0; t < 2; ++t)
#pragma unroll
            for (int r = 0; r < 16; ++r) {
                float p = __expf(st[t][r] - mnew);
                st[t][r] = p;
                psum += p;
            }
        psum += __shfl_xor(psum, 32);
        lrun = lrun * corr + psum;
#pragma unroll
        for (int n = 0; n < 2; ++n)
#pragma unroll
            for (int r = 0; r < 16; ++r) ot[n][r] *= corr;

        bf16x8_t pf[4];
#pragma unroll
        for (int t = 0; t < 2; ++t) {
            unsigned wv[8], ov[8];
#pragma unroll
            for (int j = 0; j < 8; ++j) wv[j] = pk2(st[t][2 * j], st[t][2 * j + 1]);
#pragma unroll
            for (int j = 0; j < 8; ++j) ov[j] = (unsigned)__shfl_xor((int)wv[j], 32);
#pragma unroll
            for (int sh = 0; sh < 2; ++sh) {
                int b = sh * 4;
                union { unsigned u[4]; bf16x8_t v; } u8;
                u8.u[0] = hi ? ov[b + 2] : wv[b + 0];
                u8.u[1] = hi ? ov[b + 3] : wv[b + 1];
                u8.u[2] = hi ? wv[b + 2] : ov[b + 0];
                u8.u[3] = hi ? wv[b + 3] : ov[b + 1];
                pf[t * 2 + sh] = u8.v;
            }
        }

#pragma unroll
        for (int s = 0; s < 4; ++s) {
            int gk = s * 2 + hi;
            bf16x8_t v0 = *(const bf16x8_t*)(&VS[bb][l31 * 64 + ((gk ^ (l31 & 7)) << 3)]);
            bf16x8_t v1 = *(const bf16x8_t*)(&VS[bb][(32 + l31) * 64 + ((gk ^ (l31 & 7)) << 3)]);
            ot[0] = __builtin_amdgcn_mfma_f32_32x32x16_bf16(v0, pf[s], ot[0], 0, 0, 0);
            ot[1] = __builtin_amdgcn_mfma_f32_32x32x16_bf16(v1, pf[s], ot[1], 0, 0, 0);
        }
        __syncthreads();
    }

    float invl = 1.0f / lrun;
    ushort* Os = (ushort*)&KS[0][0];
    const int wbase = w * (64 * 33);
#pragma unroll
    for (int n = 0; n < 2; ++n)
#pragma unroll
        for (int r = 0; r < 16; ++r) {
            int d = n * 32 + (r & 3) + 8 * (r >> 2) + 4 * hi;
            Os[wbase + d * 33 + l31] = __bfloat16_as_ushort(__float2bfloat16(ot[n][r] * invl));
        }
    __syncthreads();
    {
        unsigned ow2[16];
#pragma unroll
        for (int j = 0; j < 16; ++j) {
            unsigned lo = Os[wbase + (hi * 32 + 2 * j) * 33 + l31];
            unsigned hh = Os[wbase + (hi * 32 + 2 * j + 1) * 33 + l31];
            ow2[j] = lo | (hh << 16);
        }
        uint4* gd = (uint4*)(attnb + (size_t)(t0 + l31) * D_MODEL + h * DH + hi * 32);
        gd[0] = make_uint4(ow2[0], ow2[1], ow2[2], ow2[3]);
        gd[1] = make_uint4(ow2[4], ow2[5], ow2[6], ow2[7]);
        gd[2] = make_uint4(ow2[8], ow2[9], ow2[10], ow2[11]);
        gd[3] = make_uint4(ow2[12], ow2[13], ow2[14], ow2[15]);
    }
}

// ---------------------------------------------------------------------------
extern "C" void kernel_launch(void* const* d_in, const int* in_sizes, int n_in,
                              void* d_out, int out_size, void* d_ws, size_t ws_size,
                              hipStream_t stream) {
    const float* hidden = (const float*)d_in[0];
    const float* Wqkv   = (const float*)d_in[1];
    const float* Wo     = (const float*)d_in[2];
    const int*   pos    = (const int*)d_in[3];

    char* ws = (char*)d_ws;
    __hip_bfloat16* Xb    = (__hip_bfloat16*)(ws);              // 6,291,456
    __hip_bfloat16* Wqkvt = (__hip_bfloat16*)(ws + 6291456);    // 3,538,944
    __hip_bfloat16* Wot   = (__hip_bfloat16*)(ws + 9830400);    // 1,179,648
    __hip_bfloat16* Qb    = (__hip_bfloat16*)(ws + 11010048);   // 6,291,456
    __hip_bfloat16* Kb    = (__hip_bfloat16*)(ws + 17301504);   // 6,291,456
    __hip_bfloat16* Vtb   = (__hip_bfloat16*)(ws + 23592960);   // 6,291,456
    __hip_bfloat16* attnb = (__hip_bfloat16*)(ws + 29884416);   // 6,291,456
    float* out = (float*)d_out;

    // 0) all input conversions in one launch
    prep_inputs<<<3648, 256, 0, stream>>>(hidden, Wqkv, Wo, Xb, Wqkvt, Wot);

    // 1) fused QKV GEMM (8-wave) + RoPE + head-split + V-transpose
    gemm_qkv_fused<<<dim3(QKV_LD / 128, T_TOK / 128), 512, 0, stream>>>(
        Xb, Wqkvt, pos, Qb, Kb, Vtb);

    // 2) swapped-QK MFMA flash attention per 512-token segment
    attn_mfma<<<dim3(8, H_HEADS, NSEG), 128, 0, stream>>>(Qb, Kb, Vtb, attnb);

    // 3) out = attn @ Wo (64x64 tiles, 768 blocks)
    gemm_wo64<<<dim3(D_MODEL / 64, T_TOK / 64), 256, 0, stream>>>(
        attnb, Wot, out);
}

// Round 8
// 79.827 us; speedup vs baseline: 6.1981x; 1.1661x over previous
//
#include <hip/hip_runtime.h>
#include <hip/hip_bf16.h>
#include <math.h>

#define T_TOK 4096
#define D_MODEL 768
#define H_HEADS 12
#define DH 64
#define SEG 512
#define NSEG 8
#define QKV_LD 2304   // 3*D

typedef __bf16 bf16x8_t __attribute__((ext_vector_type(8)));
typedef float f32x4_t __attribute__((ext_vector_type(4)));
typedef float f32x16_t __attribute__((ext_vector_type(16)));

#define GBK 64

// compile-time-fenced workgroup barrier (rule #18: raw s_barrier is not a
// compiler fence; sched_barrier(0) pins instruction motion on both sides).
#define FENCED_BARRIER()                         \
    do {                                         \
        __builtin_amdgcn_sched_barrier(0);       \
        __builtin_amdgcn_s_barrier();            \
        __builtin_amdgcn_sched_barrier(0);       \
    } while (0)

// ---------------------------------------------------------------------------
// prep: fp32->bf16 convert of X (rows) + transpose-convert of Wqkv, Wo
// ---------------------------------------------------------------------------
__device__ __forceinline__ void tconv_body(const float* __restrict__ in,
                                           __hip_bfloat16* __restrict__ out,
                                           int N, int K, int bx, int by, int tid,
                                           float (*tile)[65]) {
    const int k0 = by * 64;
    const int n0 = bx * 64;
    const int rr = tid >> 4;
    const int cc = (tid & 15) * 4;
#pragma unroll
    for (int i = 0; i < 4; ++i) {
        int r = i * 16 + rr;
        float4 v = *(const float4*)(in + (size_t)(k0 + r) * N + n0 + cc);
        tile[r][cc] = v.x; tile[r][cc + 1] = v.y; tile[r][cc + 2] = v.z; tile[r][cc + 3] = v.w;
    }
    __syncthreads();
#pragma unroll
    for (int i = 0; i < 4; ++i) {
        int n = i * 16 + rr;
        union { __hip_bfloat16 h[4]; ushort4 u; } o;
        o.h[0] = __float2bfloat16(tile[cc + 0][n]);
        o.h[1] = __float2bfloat16(tile[cc + 1][n]);
        o.h[2] = __float2bfloat16(tile[cc + 2][n]);
        o.h[3] = __float2bfloat16(tile[cc + 3][n]);
        *(ushort4*)(out + (size_t)(n0 + n) * K + k0 + cc) = o.u;
    }
}

__global__ __launch_bounds__(256) void prep_inputs(const float* __restrict__ hidden,
                                                   const float* __restrict__ Wqkv,
                                                   const float* __restrict__ Wo,
                                                   __hip_bfloat16* __restrict__ Xb,
                                                   __hip_bfloat16* __restrict__ Wqkvt,
                                                   __hip_bfloat16* __restrict__ Wot) {
    __shared__ float tile[64][65];
    const int b = blockIdx.x;
    const int tid = threadIdx.x;
    if (b < 3072) {
        int i = b * 256 + tid;
        float4 v = ((const float4*)hidden)[i];
        union { __hip_bfloat16 h[4]; ushort4 u; } o;
        o.h[0] = __float2bfloat16(v.x); o.h[1] = __float2bfloat16(v.y);
        o.h[2] = __float2bfloat16(v.z); o.h[3] = __float2bfloat16(v.w);
        ((ushort4*)Xb)[i] = o.u;
    } else if (b < 3504) {
        int lb = b - 3072;
        tconv_body(Wqkv, Wqkvt, QKV_LD, D_MODEL, lb % 36, lb / 36, tid, tile);
    } else {
        int lb = b - 3504;
        tconv_body(Wo, Wot, D_MODEL, D_MODEL, lb % 12, lb / 12, tid, tile);
    }
}

// ---------------------------------------------------------------------------
// QKV GEMM (512 thr, 8 waves, 128x128 tile) + fused RoPE/head-split/V-transpose
// LDS tiles XOR-swizzled (T2, rule #21): linear LDS dest, inverse-swizzled
// global source (granule gc^lr), read-side granule ^(row&7).
// ---------------------------------------------------------------------------
__global__ __launch_bounds__(512) void gemm_qkv_fused(const __hip_bfloat16* __restrict__ A,
                                                      const __hip_bfloat16* __restrict__ Bt,
                                                      const int* __restrict__ pos_ids,
                                                      __hip_bfloat16* __restrict__ Qb,
                                                      __hip_bfloat16* __restrict__ Kb,
                                                      __hip_bfloat16* __restrict__ Vtb) {
    __shared__ __hip_bfloat16 As[2][128 * GBK];
    __shared__ __hip_bfloat16 Bs[2][128 * GBK];
    const int tid = threadIdx.x;
    const int lane = tid & 63;
    const int wid = tid >> 6;          // 0..7
    const int wr = wid >> 1;           // 0..3
    const int wc = wid & 1;            // 0..1
    const int m0 = blockIdx.y * 128;
    const int n0 = blockIdx.x * 128;
    const int K = D_MODEL;

    f32x4_t acc[2][4];
#pragma unroll
    for (int i = 0; i < 2; ++i)
#pragma unroll
        for (int j = 0; j < 4; ++j) acc[i][j] = (f32x4_t){0.f, 0.f, 0.f, 0.f};

    const int lr = lane >> 3;          // row within 8-row group (= row&7)
    const int gc = lane & 7;           // 16B-granule col 0..7
    const int swzc = (gc ^ lr) << 3;   // inverse-swizzled source col (elems)
    const int fr = lane & 15;
    const int l4 = lane >> 4;
    const int fsw = fr & 7;            // read-side row&7

#define STAGE_Q(buf_, k0_)                                                            \
    do {                                                                              \
        _Pragma("unroll")                                                             \
        for (int i_ = 0; i_ < 2; ++i_) {                                              \
            const int row_ = i_ * 64 + wid * 8;                                       \
            const __hip_bfloat16* ga_ = A + (size_t)(m0 + row_ + lr) * K + (k0_) + swzc; \
            __builtin_amdgcn_global_load_lds(                                         \
                (const __attribute__((address_space(1))) void*)ga_,                   \
                (__attribute__((address_space(3))) void*)(As[buf_] + row_ * GBK), 16, 0, 0); \
            const __hip_bfloat16* gb_ = Bt + (size_t)(n0 + row_ + lr) * K + (k0_) + swzc; \
            __builtin_amdgcn_global_load_lds(                                         \
                (const __attribute__((address_space(1))) void*)gb_,                   \
                (__attribute__((address_space(3))) void*)(Bs[buf_] + row_ * GBK), 16, 0, 0); \
        }                                                                             \
    } while (0)

    const int NKT = K / GBK;   // 12
    STAGE_Q(0, 0);
    for (int kt = 0; kt < NKT; ++kt) {
        const int cur = kt & 1;
        if (kt < NKT - 1) {
            STAGE_Q(cur ^ 1, (kt + 1) * GBK);
            asm volatile("s_waitcnt vmcnt(4)" ::: "memory");
        } else {
            asm volatile("s_waitcnt vmcnt(0)" ::: "memory");
        }
        FENCED_BARRIER();
#pragma unroll
        for (int kk = 0; kk < 2; ++kk) {
            const int rg = ((kk * 4 + l4) ^ fsw) << 3;   // swizzled read granule
            bf16x8_t af[2], bfr[4];
#pragma unroll
            for (int mi = 0; mi < 2; ++mi)
                af[mi] = *(const bf16x8_t*)(As[cur] + (wr * 32 + mi * 16 + fr) * GBK + rg);
#pragma unroll
            for (int ni = 0; ni < 4; ++ni)
                bfr[ni] = *(const bf16x8_t*)(Bs[cur] + (wc * 64 + ni * 16 + fr) * GBK + rg);
#pragma unroll
            for (int mi = 0; mi < 2; ++mi)
#pragma unroll
                for (int ni = 0; ni < 4; ++ni)
                    acc[mi][ni] = __builtin_amdgcn_mfma_f32_16x16x32_bf16(
                        af[mi], bfr[ni], acc[mi][ni], 0, 0, 0);
        }
        asm volatile("" ::: "memory");
        FENCED_BARRIER();
    }
#undef STAGE_Q

    // ---- fused epilogue ----
    const int colbase = n0 + wc * 64;
    const int chunk = colbase >> 6;          // 0..35
    const int part = chunk / H_HEADS;        // 0=q 1=k 2=v
    const int h = chunk % H_HEADS;
    const int trow0 = m0 + wr * 32;

    if (part == 2) {
        const int seg = trow0 >> 9;
        const int key0 = (trow0 & 511) + l4 * 4;
        __hip_bfloat16* vdst = Vtb + ((size_t)(h * NSEG + seg) * DH) * SEG;
#pragma unroll
        for (int mi = 0; mi < 2; ++mi)
#pragma unroll
            for (int ni = 0; ni < 4; ++ni) {
                int d = ni * 16 + fr;
                union { __hip_bfloat16 h2[4]; ushort4 u; } o;
#pragma unroll
                for (int j = 0; j < 4; ++j) o.h2[j] = __float2bfloat16(acc[mi][ni][j]);
                *(ushort4*)(vdst + (size_t)d * SEG + key0 + mi * 16) = o.u;
            }
    } else {
        __hip_bfloat16* dst = (part == 0) ? Qb : Kb;
        const float scale = (part == 0) ? 0.125f : 1.0f;
        const float if0 = powf(160000.0f, -(float)fr / 32.0f);
        const float if1 = powf(160000.0f, -(float)(16 + fr) / 32.0f);
#pragma unroll
        for (int mi = 0; mi < 2; ++mi)
#pragma unroll
            for (int j = 0; j < 4; ++j) {
                int t = trow0 + mi * 16 + l4 * 4 + j;
                float pos = (float)pos_ids[t];
                float s0, c0, s1, c1;
                sincosf(pos * if0, &s0, &c0);
                sincosf(pos * if1, &s1, &c1);
                __hip_bfloat16* op = dst + ((size_t)h * T_TOK + t) * DH;
                float x1, x2;
                x1 = acc[mi][0][j]; x2 = acc[mi][2][j];
                op[fr]      = __float2bfloat16((x1 * c0 - x2 * s0) * scale);
                op[fr + 32] = __float2bfloat16((x2 * c0 + x1 * s0) * scale);
                x1 = acc[mi][1][j]; x2 = acc[mi][3][j];
                op[16 + fr] = __float2bfloat16((x1 * c1 - x2 * s1) * scale);
                op[48 + fr] = __float2bfloat16((x2 * c1 + x1 * s1) * scale);
            }
    }
}

// ---------------------------------------------------------------------------
// Wo GEMM: 64x64 tile, 256 thr, 768 blocks; same T2 swizzle
// ---------------------------------------------------------------------------
__global__ __launch_bounds__(256) void gemm_wo64(const __hip_bfloat16* __restrict__ A,
                                                 const __hip_bfloat16* __restrict__ Bt,
                                                 float* __restrict__ C) {
    __shared__ __hip_bfloat16 As[2][64 * GBK];
    __shared__ __hip_bfloat16 Bs[2][64 * GBK];
    const int tid = threadIdx.x;
    const int lane = tid & 63;
    const int wid = tid >> 6;          // 0..3
    const int wr = wid >> 1, wc = wid & 1;
    const int m0 = blockIdx.y * 64;
    const int n0 = blockIdx.x * 64;
    const int K = D_MODEL;
    const int N = D_MODEL;

    f32x4_t acc[2][2];
#pragma unroll
    for (int i = 0; i < 2; ++i)
#pragma unroll
        for (int j = 0; j < 2; ++j) acc[i][j] = (f32x4_t){0.f, 0.f, 0.f, 0.f};

    const int lr = lane >> 3;
    const int gc = lane & 7;
    const int swzc = (gc ^ lr) << 3;
    const int fr = lane & 15;
    const int l4 = lane >> 4;
    const int fsw = fr & 7;

#define STAGE_W(buf_, k0_)                                                            \
    do {                                                                              \
        _Pragma("unroll")                                                             \
        for (int i_ = 0; i_ < 2; ++i_) {                                              \
            const int row_ = i_ * 32 + wid * 8;                                       \
            const __hip_bfloat16* ga_ = A + (size_t)(m0 + row_ + lr) * K + (k0_) + swzc; \
            __builtin_amdgcn_global_load_lds(                                         \
                (const __attribute__((address_space(1))) void*)ga_,                   \
                (__attribute__((address_space(3))) void*)(As[buf_] + row_ * GBK), 16, 0, 0); \
            const __hip_bfloat16* gb_ = Bt + (size_t)(n0 + row_ + lr) * K + (k0_) + swzc; \
            __builtin_amdgcn_global_load_lds(                                         \
                (const __attribute__((address_space(1))) void*)gb_,                   \
                (__attribute__((address_space(3))) void*)(Bs[buf_] + row_ * GBK), 16, 0, 0); \
        }                                                                             \
    } while (0)

    const int NKT = K / GBK;   // 12
    STAGE_W(0, 0);
    for (int kt = 0; kt < NKT; ++kt) {
        const int cur = kt & 1;
        if (kt < NKT - 1) {
            STAGE_W(cur ^ 1, (kt + 1) * GBK);
            asm volatile("s_waitcnt vmcnt(4)" ::: "memory");
        } else {
            asm volatile("s_waitcnt vmcnt(0)" ::: "memory");
        }
        FENCED_BARRIER();
#pragma unroll
        for (int kk = 0; kk < 2; ++kk) {
            const int rg = ((kk * 4 + l4) ^ fsw) << 3;
            bf16x8_t af[2], bfr[2];
#pragma unroll
            for (int mi = 0; mi < 2; ++mi)
                af[mi] = *(const bf16x8_t*)(As[cur] + (wr * 32 + mi * 16 + fr) * GBK + rg);
#pragma unroll
            for (int ni = 0; ni < 2; ++ni)
                bfr[ni] = *(const bf16x8_t*)(Bs[cur] + (wc * 32 + ni * 16 + fr) * GBK + rg);
#pragma unroll
            for (int mi = 0; mi < 2; ++mi)
#pragma unroll
                for (int ni = 0; ni < 2; ++ni)
                    acc[mi][ni] = __builtin_amdgcn_mfma_f32_16x16x32_bf16(
                        af[mi], bfr[ni], acc[mi][ni], 0, 0, 0);
        }
        asm volatile("" ::: "memory");
        FENCED_BARRIER();
    }
#undef STAGE_W

    float* Cb = C + (size_t)(m0 + wr * 32) * N + n0 + wc * 32;
#pragma unroll
    for (int mi = 0; mi < 2; ++mi)
#pragma unroll
        for (int ni = 0; ni < 2; ++ni)
#pragma unroll
            for (int j = 0; j < 4; ++j) {
                int r = mi * 16 + (lane >> 4) * 4 + j;
                Cb[(size_t)r * N + ni * 16 + fr] = acc[mi][ni][j];
            }
}

// ---------------- swapped-QK in-register-softmax flash attention ------------
__device__ __forceinline__ unsigned pk2(float a, float b) {
    unsigned ua = (unsigned)__bfloat16_as_ushort(__float2bfloat16(a));
    unsigned ub = (unsigned)__bfloat16_as_ushort(__float2bfloat16(b));
    return ua | (ub << 16);
}

__global__ __launch_bounds__(128) void attn_mfma(const __hip_bfloat16* __restrict__ Qb,
                                                 const __hip_bfloat16* __restrict__ Kb,
                                                 const __hip_bfloat16* __restrict__ Vtb,
                                                 __hip_bfloat16* __restrict__ attnb) {
    __shared__ __hip_bfloat16 KS[2][64 * 64];
    __shared__ __hip_bfloat16 VS[2][64 * 64];

    const int tid = threadIdx.x;
    const int lane = tid & 63;
    const int w = tid >> 6;
    const int hi = lane >> 5;
    const int l31 = lane & 31;
    const int qt = blockIdx.x, h = blockIdx.y, seg = blockIdx.z;
    const int t0 = seg * SEG + qt * 64 + w * 32;

    const __hip_bfloat16* kb = Kb + ((size_t)h * T_TOK + seg * SEG) * DH;
    const __hip_bfloat16* vb = Vtb + (size_t)(h * NSEG + seg) * DH * SEG;

    bf16x8_t qf[4];
    {
        const __hip_bfloat16* qp = Qb + ((size_t)h * T_TOK + t0 + l31) * DH + hi * 8;
#pragma unroll
        for (int s = 0; s < 4; ++s) qf[s] = *(const bf16x8_t*)(qp + s * 16);
    }

    const int gr = lane >> 3;
    const int gc = lane & 7;

#pragma unroll
    for (int i = 0; i < 4; ++i) {
        int G = i * 128 + w * 64;
        int rk = (G >> 3) + gr;
        const __hip_bfloat16* sk = kb + (size_t)rk * DH + ((gc ^ (rk & 7)) << 3);
        __builtin_amdgcn_global_load_lds(
            (const __attribute__((address_space(1))) void*)sk,
            (__attribute__((address_space(3))) void*)(&KS[0][G * 8]), 16, 0, 0);
        const __hip_bfloat16* sv = vb + (size_t)rk * SEG + ((gc ^ (rk & 7)) << 3);
        __builtin_amdgcn_global_load_lds(
            (const __attribute__((address_space(1))) void*)sv,
            (__attribute__((address_space(3))) void*)(&VS[0][G * 8]), 16, 0, 0);
    }
    __syncthreads();

    f32x16_t ot[2];
#pragma unroll
    for (int n = 0; n < 2; ++n)
#pragma unroll
        for (int r = 0; r < 16; ++r) ot[n][r] = 0.f;
    float mrun = -3.0e38f, lrun = 0.f;

    for (int kv = 0; kv < 8; ++kv) {
        const int bb = kv & 1;
        if (kv < 7) {
#pragma unroll
            for (int i = 0; i < 4; ++i) {
                int G = i * 128 + w * 64;
                int rk = (G >> 3) + gr;
                const __hip_bfloat16* sk = kb + (size_t)((kv + 1) * 64 + rk) * DH + ((gc ^ (rk & 7)) << 3);
                __builtin_amdgcn_global_load_lds(
                    (const __attribute__((address_space(1))) void*)sk,
                    (__attribute__((address_space(3))) void*)(&KS[bb ^ 1][G * 8]), 16, 0, 0);
                const __hip_bfloat16* sv = vb + (size_t)rk * SEG + (kv + 1) * 64 + ((gc ^ (rk & 7)) << 3);
                __builtin_amdgcn_global_load_lds(
                    (const __attribute__((address_space(1))) void*)sv,
                    (__attribute__((address_space(3))) void*)(&VS[bb ^ 1][G * 8]), 16, 0, 0);
            }
        }

        f32x16_t st[2];
#pragma unroll
        for (int t = 0; t < 2; ++t)
#pragma unroll
            for (int r = 0; r < 16; ++r) st[t][r] = 0.f;
#pragma unroll
        for (int s = 0; s < 4; ++s) {
            int gk = s * 2 + hi;
            bf16x8_t k0 = *(const bf16x8_t*)(&KS[bb][l31 * 64 + ((gk ^ (l31 & 7)) << 3)]);
            bf16x8_t k1 = *(const bf16x8_t*)(&KS[bb][(32 + l31) * 64 + ((gk ^ (l31 & 7)) << 3)]);
            st[0] = __builtin_amdgcn_mfma_f32_32x32x16_bf16(k0, qf[s], st[0], 0, 0, 0);
            st[1] = __builtin_amdgcn_mfma_f32_32x32x16_bf16(k1, qf[s], st[1], 0, 0, 0);
        }

        float tmax = st[0][0];
#pragma unroll
        for (int r = 1; r < 16; ++r) tmax = fmaxf(tmax, st[0][r]);
#pragma unroll
        for (int r = 0; r < 16; ++r) tmax = fmaxf(tmax, st[1][r]);
        tmax = fmaxf(tmax, __shfl_xor(tmax, 32));
        float mnew = fmaxf(mrun, tmax);
        float corr = __expf(mrun - mnew);
        mrun = mnew;
        float psum = 0.f;
#pragma unroll
        for (int t = 0; t < 2; ++t)
#pragma unroll
            for (int r = 0; r < 16; ++r) {
                float p = __expf(st[t][r] - mnew);
                st[t][r] = p;
                psum += p;
            }
        psum += __shfl_xor(psum, 32);
        lrun = lrun * corr + psum;
#pragma unroll
        for (int n = 0; n < 2; ++n)
#pragma unroll
            for (int r = 0; r < 16; ++r) ot[n][r] *= corr;

        bf16x8_t pf[4];
#pragma unroll
        for (int t = 0; t < 2; ++t) {
            unsigned wv[8], ov[8];
#pragma unroll
            for (int j = 0; j < 8; ++j) wv[j] = pk2(st[t][2 * j], st[t][2 * j + 1]);
#pragma unroll
            for (int j = 0; j < 8; ++j) ov[j] = (unsigned)__shfl_xor((int)wv[j], 32);
#pragma unroll
            for (int sh = 0; sh < 2; ++sh) {
                int b = sh * 4;
                union { unsigned u[4]; bf16x8_t v; } u8;
                u8.u[0] = hi ? ov[b + 2] : wv[b + 0];
                u8.u[1] = hi ? ov[b + 3] : wv[b + 1];
                u8.u[2] = hi ? wv[b + 2] : ov[b + 0];
                u8.u[3] = hi ? wv[b + 3] : ov[b + 1];
                pf[t * 2 + sh] = u8.v;
            }
        }

#pragma unroll
        for (int s = 0; s < 4; ++s) {
            int gk = s * 2 + hi;
            bf16x8_t v0 = *(const bf16x8_t*)(&VS[bb][l31 * 64 + ((gk ^ (l31 & 7)) << 3)]);
            bf16x8_t v1 = *(const bf16x8_t*)(&VS[bb][(32 + l31) * 64 + ((gk ^ (l31 & 7)) << 3)]);
            ot[0] = __builtin_amdgcn_mfma_f32_32x32x16_bf16(v0, pf[s], ot[0], 0, 0, 0);
            ot[1] = __builtin_amdgcn_mfma_f32_32x32x16_bf16(v1, pf[s], ot[1], 0, 0, 0);
        }
        __syncthreads();
    }

    float invl = 1.0f / lrun;
    ushort* Os = (ushort*)&KS[0][0];
    const int wbase = w * (64 * 33);
#pragma unroll
    for (int n = 0; n < 2; ++n)
#pragma unroll
        for (int r = 0; r < 16; ++r) {
            int d = n * 32 + (r & 3) + 8 * (r >> 2) + 4 * hi;
            Os[wbase + d * 33 + l31] = __bfloat16_as_ushort(__float2bfloat16(ot[n][r] * invl));
        }
    __syncthreads();
    {
        unsigned ow2[16];
#pragma unroll
        for (int j = 0; j < 16; ++j) {
            unsigned lo = Os[wbase + (hi * 32 + 2 * j) * 33 + l31];
            unsigned hh = Os[wbase + (hi * 32 + 2 * j + 1) * 33 + l31];
            ow2[j] = lo | (hh << 16);
        }
        uint4* gd = (uint4*)(attnb + (size_t)(t0 + l31) * D_MODEL + h * DH + hi * 32);
        gd[0] = make_uint4(ow2[0], ow2[1], ow2[2], ow2[3]);
        gd[1] = make_uint4(ow2[4], ow2[5], ow2[6], ow2[7]);
        gd[2] = make_uint4(ow2[8], ow2[9], ow2[10], ow2[11]);
        gd[3] = make_uint4(ow2[12], ow2[13], ow2[14], ow2[15]);
    }
}

// ---------------------------------------------------------------------------
extern "C" void kernel_launch(void* const* d_in, const int* in_sizes, int n_in,
                              void* d_out, int out_size, void* d_ws, size_t ws_size,
                              hipStream_t stream) {
    const float* hidden = (const float*)d_in[0];
    const float* Wqkv   = (const float*)d_in[1];
    const float* Wo     = (const float*)d_in[2];
    const int*   pos    = (const int*)d_in[3];

    char* ws = (char*)d_ws;
    __hip_bfloat16* Xb    = (__hip_bfloat16*)(ws);              // 6,291,456
    __hip_bfloat16* Wqkvt = (__hip_bfloat16*)(ws + 6291456);    // 3,538,944
    __hip_bfloat16* Wot   = (__hip_bfloat16*)(ws + 9830400);    // 1,179,648
    __hip_bfloat16* Qb    = (__hip_bfloat16*)(ws + 11010048);   // 6,291,456
    __hip_bfloat16* Kb    = (__hip_bfloat16*)(ws + 17301504);   // 6,291,456
    __hip_bfloat16* Vtb   = (__hip_bfloat16*)(ws + 23592960);   // 6,291,456
    __hip_bfloat16* attnb = (__hip_bfloat16*)(ws + 29884416);   // 6,291,456
    float* out = (float*)d_out;

    prep_inputs<<<3648, 256, 0, stream>>>(hidden, Wqkv, Wo, Xb, Wqkvt, Wot);

    gemm_qkv_fused<<<dim3(QKV_LD / 128, T_TOK / 128), 512, 0, stream>>>(
        Xb, Wqkvt, pos, Qb, Kb, Vtb);

    attn_mfma<<<dim3(8, H_HEADS, NSEG), 128, 0, stream>>>(Qb, Kb, Vtb, attnb);

    gemm_wo64<<<dim3(D_MODEL / 64, T_TOK / 64), 256, 0, stream>>>(
        attnb, Wot, out);
}

// Round 9
// 77.176 us; speedup vs baseline: 6.4110x; 1.0343x over previous
//
#include <hip/hip_runtime.h>
#include <hip/hip_bf16.h>
#include <math.h>

#define T_TOK 4096
#define D_MODEL 768
#define H_HEADS 12
#define DH 64
#define SEG 512
#define NSEG 8
#define QKV_LD 2304   // 3*D

typedef __bf16 bf16x8_t __attribute__((ext_vector_type(8)));
typedef float f32x4_t __attribute__((ext_vector_type(4)));
typedef float f32x16_t __attribute__((ext_vector_type(16)));

#define GBK 64
// Q pre-scale: 1/sqrt(64) * log2(e)  (softmax computed in base-2 space)
#define QSCALE 0.18033688011112042f

// compile-time-fenced workgroup barrier (rule #18)
#define FENCED_BARRIER()                         \
    do {                                         \
        __builtin_amdgcn_sched_barrier(0);       \
        __builtin_amdgcn_s_barrier();            \
        __builtin_amdgcn_sched_barrier(0);       \
    } while (0)

// ---------------------------------------------------------------------------
// prep: fp32->bf16 convert of X (rows) + transpose-convert of Wqkv, Wo
// ---------------------------------------------------------------------------
__device__ __forceinline__ void tconv_body(const float* __restrict__ in,
                                           __hip_bfloat16* __restrict__ out,
                                           int N, int K, int bx, int by, int tid,
                                           float (*tile)[65]) {
    const int k0 = by * 64;
    const int n0 = bx * 64;
    const int rr = tid >> 4;
    const int cc = (tid & 15) * 4;
#pragma unroll
    for (int i = 0; i < 4; ++i) {
        int r = i * 16 + rr;
        float4 v = *(const float4*)(in + (size_t)(k0 + r) * N + n0 + cc);
        tile[r][cc] = v.x; tile[r][cc + 1] = v.y; tile[r][cc + 2] = v.z; tile[r][cc + 3] = v.w;
    }
    __syncthreads();
#pragma unroll
    for (int i = 0; i < 4; ++i) {
        int n = i * 16 + rr;
        union { __hip_bfloat16 h[4]; ushort4 u; } o;
        o.h[0] = __float2bfloat16(tile[cc + 0][n]);
        o.h[1] = __float2bfloat16(tile[cc + 1][n]);
        o.h[2] = __float2bfloat16(tile[cc + 2][n]);
        o.h[3] = __float2bfloat16(tile[cc + 3][n]);
        *(ushort4*)(out + (size_t)(n0 + n) * K + k0 + cc) = o.u;
    }
}

__global__ __launch_bounds__(256) void prep_inputs(const float* __restrict__ hidden,
                                                   const float* __restrict__ Wqkv,
                                                   const float* __restrict__ Wo,
                                                   __hip_bfloat16* __restrict__ Xb,
                                                   __hip_bfloat16* __restrict__ Wqkvt,
                                                   __hip_bfloat16* __restrict__ Wot) {
    __shared__ float tile[64][65];
    const int b = blockIdx.x;
    const int tid = threadIdx.x;
    if (b < 3072) {
        int i = b * 256 + tid;
        float4 v = ((const float4*)hidden)[i];
        union { __hip_bfloat16 h[4]; ushort4 u; } o;
        o.h[0] = __float2bfloat16(v.x); o.h[1] = __float2bfloat16(v.y);
        o.h[2] = __float2bfloat16(v.z); o.h[3] = __float2bfloat16(v.w);
        ((ushort4*)Xb)[i] = o.u;
    } else if (b < 3504) {
        int lb = b - 3072;
        tconv_body(Wqkv, Wqkvt, QKV_LD, D_MODEL, lb % 36, lb / 36, tid, tile);
    } else {
        int lb = b - 3504;
        tconv_body(Wo, Wot, D_MODEL, D_MODEL, lb % 12, lb / 12, tid, tile);
    }
}

// ---------------------------------------------------------------------------
// QKV GEMM (512 thr, 8 waves, 128x128 tile) + fused RoPE/head-split/V-transpose
// T2 LDS swizzle + T1 chunked XCD remap (576 = 8 x 72, bijective).
// ---------------------------------------------------------------------------
__global__ __launch_bounds__(512) void gemm_qkv_fused(const __hip_bfloat16* __restrict__ A,
                                                      const __hip_bfloat16* __restrict__ Bt,
                                                      const int* __restrict__ pos_ids,
                                                      __hip_bfloat16* __restrict__ Qb,
                                                      __hip_bfloat16* __restrict__ Kb,
                                                      __hip_bfloat16* __restrict__ Vtb) {
    __shared__ __hip_bfloat16 As[2][128 * GBK];
    __shared__ __hip_bfloat16 Bs[2][128 * GBK];
    const int tid = threadIdx.x;
    const int lane = tid & 63;
    const int wid = tid >> 6;          // 0..7
    const int wr = wid >> 1;           // 0..3
    const int wc = wid & 1;            // 0..1
    // XCD-chunked remap: each XCD gets 4 M-panels x all 18 N-tiles
    const int orig = blockIdx.y * 18 + blockIdx.x;   // 0..575
    const int wg = (orig & 7) * 72 + (orig >> 3);
    const int m0 = (wg / 18) * 128;
    const int n0 = (wg % 18) * 128;
    const int K = D_MODEL;

    f32x4_t acc[2][4];
#pragma unroll
    for (int i = 0; i < 2; ++i)
#pragma unroll
        for (int j = 0; j < 4; ++j) acc[i][j] = (f32x4_t){0.f, 0.f, 0.f, 0.f};

    const int lr = lane >> 3;          // row within 8-row group
    const int gc = lane & 7;           // 16B-granule col
    const int swzc = (gc ^ lr) << 3;   // inverse-swizzled source col (elems)
    const int fr = lane & 15;
    const int l4 = lane >> 4;
    const int fsw = fr & 7;

#define STAGE_Q(buf_, k0_)                                                            \
    do {                                                                              \
        _Pragma("unroll")                                                             \
        for (int i_ = 0; i_ < 2; ++i_) {                                              \
            const int row_ = i_ * 64 + wid * 8;                                       \
            const __hip_bfloat16* ga_ = A + (size_t)(m0 + row_ + lr) * K + (k0_) + swzc; \
            __builtin_amdgcn_global_load_lds(                                         \
                (const __attribute__((address_space(1))) void*)ga_,                   \
                (__attribute__((address_space(3))) void*)(As[buf_] + row_ * GBK), 16, 0, 0); \
            const __hip_bfloat16* gb_ = Bt + (size_t)(n0 + row_ + lr) * K + (k0_) + swzc; \
            __builtin_amdgcn_global_load_lds(                                         \
                (const __attribute__((address_space(1))) void*)gb_,                   \
                (__attribute__((address_space(3))) void*)(Bs[buf_] + row_ * GBK), 16, 0, 0); \
        }                                                                             \
    } while (0)

    const int NKT = K / GBK;   // 12
    STAGE_Q(0, 0);
    for (int kt = 0; kt < NKT; ++kt) {
        const int cur = kt & 1;
        if (kt < NKT - 1) {
            STAGE_Q(cur ^ 1, (kt + 1) * GBK);
            asm volatile("s_waitcnt vmcnt(4)" ::: "memory");
        } else {
            asm volatile("s_waitcnt vmcnt(0)" ::: "memory");
        }
        FENCED_BARRIER();
#pragma unroll
        for (int kk = 0; kk < 2; ++kk) {
            const int rg = ((kk * 4 + l4) ^ fsw) << 3;
            bf16x8_t af[2], bfr[4];
#pragma unroll
            for (int mi = 0; mi < 2; ++mi)
                af[mi] = *(const bf16x8_t*)(As[cur] + (wr * 32 + mi * 16 + fr) * GBK + rg);
#pragma unroll
            for (int ni = 0; ni < 4; ++ni)
                bfr[ni] = *(const bf16x8_t*)(Bs[cur] + (wc * 64 + ni * 16 + fr) * GBK + rg);
#pragma unroll
            for (int mi = 0; mi < 2; ++mi)
#pragma unroll
                for (int ni = 0; ni < 4; ++ni)
                    acc[mi][ni] = __builtin_amdgcn_mfma_f32_16x16x32_bf16(
                        af[mi], bfr[ni], acc[mi][ni], 0, 0, 0);
        }
        asm volatile("" ::: "memory");
        FENCED_BARRIER();
    }
#undef STAGE_Q

    // ---- fused epilogue ----
    const int colbase = n0 + wc * 64;
    const int chunk = colbase >> 6;          // 0..35
    const int part = chunk / H_HEADS;        // 0=q 1=k 2=v
    const int h = chunk % H_HEADS;
    const int trow0 = m0 + wr * 32;

    if (part == 2) {
        const int seg = trow0 >> 9;
        const int key0 = (trow0 & 511) + l4 * 4;
        __hip_bfloat16* vdst = Vtb + ((size_t)(h * NSEG + seg) * DH) * SEG;
#pragma unroll
        for (int mi = 0; mi < 2; ++mi)
#pragma unroll
            for (int ni = 0; ni < 4; ++ni) {
                int d = ni * 16 + fr;
                union { __hip_bfloat16 h2[4]; ushort4 u; } o;
#pragma unroll
                for (int j = 0; j < 4; ++j) o.h2[j] = __float2bfloat16(acc[mi][ni][j]);
                *(ushort4*)(vdst + (size_t)d * SEG + key0 + mi * 16) = o.u;
            }
    } else {
        __hip_bfloat16* dst = (part == 0) ? Qb : Kb;
        const float scale = (part == 0) ? QSCALE : 1.0f;
        const float if0 = powf(160000.0f, -(float)fr / 32.0f);
        const float if1 = powf(160000.0f, -(float)(16 + fr) / 32.0f);
#pragma unroll
        for (int mi = 0; mi < 2; ++mi)
#pragma unroll
            for (int j = 0; j < 4; ++j) {
                int t = trow0 + mi * 16 + l4 * 4 + j;
                float pos = (float)pos_ids[t];
                float s0, c0, s1, c1;
                sincosf(pos * if0, &s0, &c0);
                sincosf(pos * if1, &s1, &c1);
                __hip_bfloat16* op = dst + ((size_t)h * T_TOK + t) * DH;
                float x1, x2;
                x1 = acc[mi][0][j]; x2 = acc[mi][2][j];
                op[fr]      = __float2bfloat16((x1 * c0 - x2 * s0) * scale);
                op[fr + 32] = __float2bfloat16((x2 * c0 + x1 * s0) * scale);
                x1 = acc[mi][1][j]; x2 = acc[mi][3][j];
                op[16 + fr] = __float2bfloat16((x1 * c1 - x2 * s1) * scale);
                op[48 + fr] = __float2bfloat16((x2 * c1 + x1 * s1) * scale);
            }
    }
}

// ---------------------------------------------------------------------------
// Wo GEMM: 64x64 tile, 256 thr, 768 blocks; T2 swizzle + T1 XCD remap
// ---------------------------------------------------------------------------
__global__ __launch_bounds__(256) void gemm_wo64(const __hip_bfloat16* __restrict__ A,
                                                 const __hip_bfloat16* __restrict__ Bt,
                                                 float* __restrict__ C) {
    __shared__ __hip_bfloat16 As[2][64 * GBK];
    __shared__ __hip_bfloat16 Bs[2][64 * GBK];
    const int tid = threadIdx.x;
    const int lane = tid & 63;
    const int wid = tid >> 6;          // 0..3
    const int wr = wid >> 1, wc = wid & 1;
    const int orig = blockIdx.y * 12 + blockIdx.x;   // 0..767
    const int wg = (orig & 7) * 96 + (orig >> 3);
    const int m0 = (wg / 12) * 64;
    const int n0 = (wg % 12) * 64;
    const int K = D_MODEL;
    const int N = D_MODEL;

    f32x4_t acc[2][2];
#pragma unroll
    for (int i = 0; i < 2; ++i)
#pragma unroll
        for (int j = 0; j < 2; ++j) acc[i][j] = (f32x4_t){0.f, 0.f, 0.f, 0.f};

    const int lr = lane >> 3;
    const int gc = lane & 7;
    const int swzc = (gc ^ lr) << 3;
    const int fr = lane & 15;
    const int l4 = lane >> 4;
    const int fsw = fr & 7;

#define STAGE_W(buf_, k0_)                                                            \
    do {                                                                              \
        _Pragma("unroll")                                                             \
        for (int i_ = 0; i_ < 2; ++i_) {                                              \
            const int row_ = i_ * 32 + wid * 8;                                       \
            const __hip_bfloat16* ga_ = A + (size_t)(m0 + row_ + lr) * K + (k0_) + swzc; \
            __builtin_amdgcn_global_load_lds(                                         \
                (const __attribute__((address_space(1))) void*)ga_,                   \
                (__attribute__((address_space(3))) void*)(As[buf_] + row_ * GBK), 16, 0, 0); \
            const __hip_bfloat16* gb_ = Bt + (size_t)(n0 + row_ + lr) * K + (k0_) + swzc; \
            __builtin_amdgcn_global_load_lds(                                         \
                (const __attribute__((address_space(1))) void*)gb_,                   \
                (__attribute__((address_space(3))) void*)(Bs[buf_] + row_ * GBK), 16, 0, 0); \
        }                                                                             \
    } while (0)

    const int NKT = K / GBK;   // 12
    STAGE_W(0, 0);
    for (int kt = 0; kt < NKT; ++kt) {
        const int cur = kt & 1;
        if (kt < NKT - 1) {
            STAGE_W(cur ^ 1, (kt + 1) * GBK);
            asm volatile("s_waitcnt vmcnt(4)" ::: "memory");
        } else {
            asm volatile("s_waitcnt vmcnt(0)" ::: "memory");
        }
        FENCED_BARRIER();
#pragma unroll
        for (int kk = 0; kk < 2; ++kk) {
            const int rg = ((kk * 4 + l4) ^ fsw) << 3;
            bf16x8_t af[2], bfr[2];
#pragma unroll
            for (int mi = 0; mi < 2; ++mi)
                af[mi] = *(const bf16x8_t*)(As[cur] + (wr * 32 + mi * 16 + fr) * GBK + rg);
#pragma unroll
            for (int ni = 0; ni < 2; ++ni)
                bfr[ni] = *(const bf16x8_t*)(Bs[cur] + (wc * 32 + ni * 16 + fr) * GBK + rg);
#pragma unroll
            for (int mi = 0; mi < 2; ++mi)
#pragma unroll
                for (int ni = 0; ni < 2; ++ni)
                    acc[mi][ni] = __builtin_amdgcn_mfma_f32_16x16x32_bf16(
                        af[mi], bfr[ni], acc[mi][ni], 0, 0, 0);
        }
        asm volatile("" ::: "memory");
        FENCED_BARRIER();
    }
#undef STAGE_W

    float* Cb = C + (size_t)(m0 + wr * 32) * N + n0 + wc * 32;
#pragma unroll
    for (int mi = 0; mi < 2; ++mi)
#pragma unroll
        for (int ni = 0; ni < 2; ++ni)
#pragma unroll
            for (int j = 0; j < 4; ++j) {
                int r = mi * 16 + (lane >> 4) * 4 + j;
                Cb[(size_t)r * N + ni * 16 + fr] = acc[mi][ni][j];
            }
}

// ---------------- swapped-QK in-register-softmax flash attention ------------
// 1D grid 768 with chunked XCD remap; softmax in base-2 space; defer-max.
__device__ __forceinline__ unsigned pk2(float a, float b) {
    unsigned ua = (unsigned)__bfloat16_as_ushort(__float2bfloat16(a));
    unsigned ub = (unsigned)__bfloat16_as_ushort(__float2bfloat16(b));
    return ua | (ub << 16);
}

__global__ __launch_bounds__(128) void attn_mfma(const __hip_bfloat16* __restrict__ Qb,
                                                 const __hip_bfloat16* __restrict__ Kb,
                                                 const __hip_bfloat16* __restrict__ Vtb,
                                                 __hip_bfloat16* __restrict__ attnb) {
    __shared__ __hip_bfloat16 KS[2][64 * 64];
    __shared__ __hip_bfloat16 VS[2][64 * 64];

    const int tid = threadIdx.x;
    const int lane = tid & 63;
    const int w = tid >> 6;
    const int hi = lane >> 5;
    const int l31 = lane & 31;
    // chunked XCD remap: 12 complete (h,seg) groups per XCD -> K/V L2-resident
    const int orig = blockIdx.x;                 // 0..767
    const int wg = (orig & 7) * 96 + (orig >> 3);
    const int qt = wg & 7;
    const int hs = wg >> 3;                      // 0..95
    const int h = hs % H_HEADS;
    const int seg = hs / H_HEADS;
    const int t0 = seg * SEG + qt * 64 + w * 32;

    const __hip_bfloat16* kb = Kb + ((size_t)h * T_TOK + seg * SEG) * DH;
    const __hip_bfloat16* vb = Vtb + (size_t)(h * NSEG + seg) * DH * SEG;

    bf16x8_t qf[4];
    {
        const __hip_bfloat16* qp = Qb + ((size_t)h * T_TOK + t0 + l31) * DH + hi * 8;
#pragma unroll
        for (int s = 0; s < 4; ++s) qf[s] = *(const bf16x8_t*)(qp + s * 16);
    }

    const int gr = lane >> 3;
    const int gc = lane & 7;

#pragma unroll
    for (int i = 0; i < 4; ++i) {
        int G = i * 128 + w * 64;
        int rk = (G >> 3) + gr;
        const __hip_bfloat16* sk = kb + (size_t)rk * DH + ((gc ^ (rk & 7)) << 3);
        __builtin_amdgcn_global_load_lds(
            (const __attribute__((address_space(1))) void*)sk,
            (__attribute__((address_space(3))) void*)(&KS[0][G * 8]), 16, 0, 0);
        const __hip_bfloat16* sv = vb + (size_t)rk * SEG + ((gc ^ (rk & 7)) << 3);
        __builtin_amdgcn_global_load_lds(
            (const __attribute__((address_space(1))) void*)sv,
            (__attribute__((address_space(3))) void*)(&VS[0][G * 8]), 16, 0, 0);
    }
    __syncthreads();

    f32x16_t ot[2];
#pragma unroll
    for (int n = 0; n < 2; ++n)
#pragma unroll
        for (int r = 0; r < 16; ++r) ot[n][r] = 0.f;
    float mrun = -3.0e38f, lrun = 0.f;

    for (int kv = 0; kv < 8; ++kv) {
        const int bb = kv & 1;
        if (kv < 7) {
#pragma unroll
            for (int i = 0; i < 4; ++i) {
                int G = i * 128 + w * 64;
                int rk = (G >> 3) + gr;
                const __hip_bfloat16* sk = kb + (size_t)((kv + 1) * 64 + rk) * DH + ((gc ^ (rk & 7)) << 3);
                __builtin_amdgcn_global_load_lds(
                    (const __attribute__((address_space(1))) void*)sk,
                    (__attribute__((address_space(3))) void*)(&KS[bb ^ 1][G * 8]), 16, 0, 0);
                const __hip_bfloat16* sv = vb + (size_t)rk * SEG + (kv + 1) * 64 + ((gc ^ (rk & 7)) << 3);
                __builtin_amdgcn_global_load_lds(
                    (const __attribute__((address_space(1))) void*)sv,
                    (__attribute__((address_space(3))) void*)(&VS[bb ^ 1][G * 8]), 16, 0, 0);
            }
        }

        f32x16_t st[2];
#pragma unroll
        for (int t = 0; t < 2; ++t)
#pragma unroll
            for (int r = 0; r < 16; ++r) st[t][r] = 0.f;
#pragma unroll
        for (int s = 0; s < 4; ++s) {
            int gk = s * 2 + hi;
            bf16x8_t k0 = *(const bf16x8_t*)(&KS[bb][l31 * 64 + ((gk ^ (l31 & 7)) << 3)]);
            bf16x8_t k1 = *(const bf16x8_t*)(&KS[bb][(32 + l31) * 64 + ((gk ^ (l31 & 7)) << 3)]);
            st[0] = __builtin_amdgcn_mfma_f32_32x32x16_bf16(k0, qf[s], st[0], 0, 0, 0);
            st[1] = __builtin_amdgcn_mfma_f32_32x32x16_bf16(k1, qf[s], st[1], 0, 0, 0);
        }

        // scores are already in log2 space (QSCALE folded log2e)
        float tmax = st[0][0];
#pragma unroll
        for (int r = 1; r < 16; ++r) tmax = fmaxf(tmax, st[0][r]);
#pragma unroll
        for (int r = 0; r < 16; ++r) tmax = fmaxf(tmax, st[1][r]);
        tmax = fmaxf(tmax, __shfl_xor(tmax, 32));

        // defer-max (T13): skip O/l rescale when max growth <= 8 (P <= 2^8)
        if (!__all(tmax <= mrun + 8.0f)) {
            float mnew = fmaxf(mrun, tmax);
            float corr = exp2f(mrun - mnew);
            lrun *= corr;
#pragma unroll
            for (int n = 0; n < 2; ++n)
#pragma unroll
                for (int r = 0; r < 16; ++r) ot[n][r] *= corr;
            mrun = mnew;
        }
        float psum = 0.f;
#pragma unroll
        for (int t = 0; t < 2; ++t)
#pragma unroll
            for (int r = 0; r < 16; ++r) {
                float p = exp2f(st[t][r] - mrun);
                st[t][r] = p;
                psum += p;
            }
        psum += __shfl_xor(psum, 32);
        lrun += psum;

        bf16x8_t pf[4];
#pragma unroll
        for (int t = 0; t < 2; ++t) {
            unsigned wv[8], ov[8];
#pragma unroll
            for (int j = 0; j < 8; ++j) wv[j] = pk2(st[t][2 * j], st[t][2 * j + 1]);
#pragma unroll
            for (int j = 0; j < 8; ++j) ov[j] = (unsigned)__shfl_xor((int)wv[j], 32);
#pragma unroll
            for (int sh = 0; sh < 2; ++sh) {
                int b = sh * 4;
                union { unsigned u[4]; bf16x8_t v; } u8;
                u8.u[0] = hi ? ov[b + 2] : wv[b + 0];
                u8.u[1] = hi ? ov[b + 3] : wv[b + 1];
                u8.u[2] = hi ? wv[b + 2] : ov[b + 0];
                u8.u[3] = hi ? wv[b + 3] : ov[b + 1];
                pf[t * 2 + sh] = u8.v;
            }
        }

#pragma unroll
        for (int s = 0; s < 4; ++s) {
            int gk = s * 2 + hi;
            bf16x8_t v0 = *(const bf16x8_t*)(&VS[bb][l31 * 64 + ((gk ^ (l31 & 7)) << 3)]);
            bf16x8_t v1 = *(const bf16x8_t*)(&VS[bb][(32 + l31) * 64 + ((gk ^ (l31 & 7)) << 3)]);
            ot[0] = __builtin_amdgcn_mfma_f32_32x32x16_bf16(v0, pf[s], ot[0], 0, 0, 0);
            ot[1] = __builtin_amdgcn_mfma_f32_32x32x16_bf16(v1, pf[s], ot[1], 0, 0, 0);
        }
        __syncthreads();
    }

    float invl = 1.0f / lrun;
    ushort* Os = (ushort*)&KS[0][0];
    const int wbase = w * (64 * 33);
#pragma unroll
    for (int n = 0; n < 2; ++n)
#pragma unroll
        for (int r = 0; r < 16; ++r) {
            int d = n * 32 + (r & 3) + 8 * (r >> 2) + 4 * hi;
            Os[wbase + d * 33 + l31] = __bfloat16_as_ushort(__float2bfloat16(ot[n][r] * invl));
        }
    __syncthreads();
    {
        unsigned ow2[16];
#pragma unroll
        for (int j = 0; j < 16; ++j) {
            unsigned lo = Os[wbase + (hi * 32 + 2 * j) * 33 + l31];
            unsigned hh = Os[wbase + (hi * 32 + 2 * j + 1) * 33 + l31];
            ow2[j] = lo | (hh << 16);
        }
        uint4* gd = (uint4*)(attnb + (size_t)(t0 + l31) * D_MODEL + h * DH + hi * 32);
        gd[0] = make_uint4(ow2[0], ow2[1], ow2[2], ow2[3]);
        gd[1] = make_uint4(ow2[4], ow2[5], ow2[6], ow2[7]);
        gd[2] = make_uint4(ow2[8], ow2[9], ow2[10], ow2[11]);
        gd[3] = make_uint4(ow2[12], ow2[13], ow2[14], ow2[15]);
    }
}

// ---------------------------------------------------------------------------
extern "C" void kernel_launch(void* const* d_in, const int* in_sizes, int n_in,
                              void* d_out, int out_size, void* d_ws, size_t ws_size,
                              hipStream_t stream) {
    const float* hidden = (const float*)d_in[0];
    const float* Wqkv   = (const float*)d_in[1];
    const float* Wo     = (const float*)d_in[2];
    const int*   pos    = (const int*)d_in[3];

    char* ws = (char*)d_ws;
    __hip_bfloat16* Xb    = (__hip_bfloat16*)(ws);              // 6,291,456
    __hip_bfloat16* Wqkvt = (__hip_bfloat16*)(ws + 6291456);    // 3,538,944
    __hip_bfloat16* Wot   = (__hip_bfloat16*)(ws + 9830400);    // 1,179,648
    __hip_bfloat16* Qb    = (__hip_bfloat16*)(ws + 11010048);   // 6,291,456
    __hip_bfloat16* Kb    = (__hip_bfloat16*)(ws + 17301504);   // 6,291,456
    __hip_bfloat16* Vtb   = (__hip_bfloat16*)(ws + 23592960);   // 6,291,456
    __hip_bfloat16* attnb = (__hip_bfloat16*)(ws + 29884416);   // 6,291,456
    float* out = (float*)d_out;

    prep_inputs<<<3648, 256, 0, stream>>>(hidden, Wqkv, Wo, Xb, Wqkvt, Wot);

    gemm_qkv_fused<<<dim3(QKV_LD / 128, T_TOK / 128), 512, 0, stream>>>(
        Xb, Wqkvt, pos, Qb, Kb, Vtb);

    attn_mfma<<<768, 128, 0, stream>>>(Qb, Kb, Vtb, attnb);

    gemm_wo64<<<dim3(D_MODEL / 64, T_TOK / 64), 256, 0, stream>>>(
        attnb, Wot, out);
}

// Round 10
// 75.677 us; speedup vs baseline: 6.5379x; 1.0198x over previous
//
#include <hip/hip_runtime.h>
#include <hip/hip_bf16.h>
#include <math.h>

#define T_TOK 4096
#define D_MODEL 768
#define H_HEADS 12
#define DH 64
#define SEG 512
#define NSEG 8
#define QKV_LD 2304   // 3*D

typedef __bf16 bf16x8_t __attribute__((ext_vector_type(8)));
typedef float f32x4_t __attribute__((ext_vector_type(4)));
typedef float f32x16_t __attribute__((ext_vector_type(16)));

#define GBK 64
// Q pre-scale: 1/sqrt(64) * log2(e)  (softmax computed in base-2 space)
#define QSCALE 0.18033688011112042f

// compile-time-fenced workgroup barrier (rule #18)
#define FENCED_BARRIER()                         \
    do {                                         \
        __builtin_amdgcn_sched_barrier(0);       \
        __builtin_amdgcn_s_barrier();            \
        __builtin_amdgcn_sched_barrier(0);       \
    } while (0)

// ---------------------------------------------------------------------------
// prep: fp32->bf16 convert of X + transpose-convert of Wqkv, Wo + RoPE table
// grid: [0,3072) X ; [3072,3504) Wqkv^T ; [3504,3648) Wo^T ; [3648,4160) table
// ---------------------------------------------------------------------------
__device__ __forceinline__ void tconv_body(const float* __restrict__ in,
                                           __hip_bfloat16* __restrict__ out,
                                           int N, int K, int bx, int by, int tid,
                                           float (*tile)[65]) {
    const int k0 = by * 64;
    const int n0 = bx * 64;
    const int rr = tid >> 4;
    const int cc = (tid & 15) * 4;
#pragma unroll
    for (int i = 0; i < 4; ++i) {
        int r = i * 16 + rr;
        float4 v = *(const float4*)(in + (size_t)(k0 + r) * N + n0 + cc);
        tile[r][cc] = v.x; tile[r][cc + 1] = v.y; tile[r][cc + 2] = v.z; tile[r][cc + 3] = v.w;
    }
    __syncthreads();
#pragma unroll
    for (int i = 0; i < 4; ++i) {
        int n = i * 16 + rr;
        union { __hip_bfloat16 h[4]; ushort4 u; } o;
        o.h[0] = __float2bfloat16(tile[cc + 0][n]);
        o.h[1] = __float2bfloat16(tile[cc + 1][n]);
        o.h[2] = __float2bfloat16(tile[cc + 2][n]);
        o.h[3] = __float2bfloat16(tile[cc + 3][n]);
        *(ushort4*)(out + (size_t)(n0 + n) * K + k0 + cc) = o.u;
    }
}

__global__ __launch_bounds__(256) void prep_inputs(const float* __restrict__ hidden,
                                                   const float* __restrict__ Wqkv,
                                                   const float* __restrict__ Wo,
                                                   const int* __restrict__ pos_ids,
                                                   __hip_bfloat16* __restrict__ Xb,
                                                   __hip_bfloat16* __restrict__ Wqkvt,
                                                   __hip_bfloat16* __restrict__ Wot,
                                                   float2* __restrict__ rtab) {
    __shared__ float tile[64][65];
    const int b = blockIdx.x;
    const int tid = threadIdx.x;
    if (b < 3072) {
        int i = b * 256 + tid;
        float4 v = ((const float4*)hidden)[i];
        union { __hip_bfloat16 h[4]; ushort4 u; } o;
        o.h[0] = __float2bfloat16(v.x); o.h[1] = __float2bfloat16(v.y);
        o.h[2] = __float2bfloat16(v.z); o.h[3] = __float2bfloat16(v.w);
        ((ushort4*)Xb)[i] = o.u;
    } else if (b < 3504) {
        int lb = b - 3072;
        tconv_body(Wqkv, Wqkvt, QKV_LD, D_MODEL, lb % 36, lb / 36, tid, tile);
    } else if (b < 3648) {
        int lb = b - 3504;
        tconv_body(Wo, Wot, D_MODEL, D_MODEL, lb % 12, lb / 12, tid, tile);
    } else {
        int idx = (b - 3648) * 256 + tid;   // T*32 = 131072 exactly
        int t = idx >> 5;
        int i = idx & 31;
        float pos = (float)pos_ids[t];
        float inv_freq = powf(160000.0f, -(float)i / 32.0f);
        float s, c;
        sincosf(pos * inv_freq, &s, &c);
        rtab[idx] = make_float2(c, s);
    }
}

// ---------------------------------------------------------------------------
// QKV GEMM (512 thr, 8 waves, 128x128 tile) + fused RoPE/head-split/V-transpose
// T2 LDS swizzle + T1 chunked XCD remap; RoPE via precomputed table.
// ---------------------------------------------------------------------------
__global__ __launch_bounds__(512) void gemm_qkv_fused(const __hip_bfloat16* __restrict__ A,
                                                      const __hip_bfloat16* __restrict__ Bt,
                                                      const float2* __restrict__ rtab,
                                                      __hip_bfloat16* __restrict__ Qb,
                                                      __hip_bfloat16* __restrict__ Kb,
                                                      __hip_bfloat16* __restrict__ Vtb) {
    __shared__ __hip_bfloat16 As[2][128 * GBK];
    __shared__ __hip_bfloat16 Bs[2][128 * GBK];
    const int tid = threadIdx.x;
    const int lane = tid & 63;
    const int wid = tid >> 6;          // 0..7
    const int wr = wid >> 1;           // 0..3
    const int wc = wid & 1;            // 0..1
    const int orig = blockIdx.y * 18 + blockIdx.x;   // 0..575
    const int wg = (orig & 7) * 72 + (orig >> 3);
    const int m0 = (wg / 18) * 128;
    const int n0 = (wg % 18) * 128;
    const int K = D_MODEL;

    f32x4_t acc[2][4];
#pragma unroll
    for (int i = 0; i < 2; ++i)
#pragma unroll
        for (int j = 0; j < 4; ++j) acc[i][j] = (f32x4_t){0.f, 0.f, 0.f, 0.f};

    const int lr = lane >> 3;
    const int gc = lane & 7;
    const int swzc = (gc ^ lr) << 3;
    const int fr = lane & 15;
    const int l4 = lane >> 4;
    const int fsw = fr & 7;

#define STAGE_Q(buf_, k0_)                                                            \
    do {                                                                              \
        _Pragma("unroll")                                                             \
        for (int i_ = 0; i_ < 2; ++i_) {                                              \
            const int row_ = i_ * 64 + wid * 8;                                       \
            const __hip_bfloat16* ga_ = A + (size_t)(m0 + row_ + lr) * K + (k0_) + swzc; \
            __builtin_amdgcn_global_load_lds(                                         \
                (const __attribute__((address_space(1))) void*)ga_,                   \
                (__attribute__((address_space(3))) void*)(As[buf_] + row_ * GBK), 16, 0, 0); \
            const __hip_bfloat16* gb_ = Bt + (size_t)(n0 + row_ + lr) * K + (k0_) + swzc; \
            __builtin_amdgcn_global_load_lds(                                         \
                (const __attribute__((address_space(1))) void*)gb_,                   \
                (__attribute__((address_space(3))) void*)(Bs[buf_] + row_ * GBK), 16, 0, 0); \
        }                                                                             \
    } while (0)

    const int NKT = K / GBK;   // 12
    STAGE_Q(0, 0);
    for (int kt = 0; kt < NKT; ++kt) {
        const int cur = kt & 1;
        if (kt < NKT - 1) {
            STAGE_Q(cur ^ 1, (kt + 1) * GBK);
            asm volatile("s_waitcnt vmcnt(4)" ::: "memory");
        } else {
            asm volatile("s_waitcnt vmcnt(0)" ::: "memory");
        }
        FENCED_BARRIER();
#pragma unroll
        for (int kk = 0; kk < 2; ++kk) {
            const int rg = ((kk * 4 + l4) ^ fsw) << 3;
            bf16x8_t af[2], bfr[4];
#pragma unroll
            for (int mi = 0; mi < 2; ++mi)
                af[mi] = *(const bf16x8_t*)(As[cur] + (wr * 32 + mi * 16 + fr) * GBK + rg);
#pragma unroll
            for (int ni = 0; ni < 4; ++ni)
                bfr[ni] = *(const bf16x8_t*)(Bs[cur] + (wc * 64 + ni * 16 + fr) * GBK + rg);
#pragma unroll
            for (int mi = 0; mi < 2; ++mi)
#pragma unroll
                for (int ni = 0; ni < 4; ++ni)
                    acc[mi][ni] = __builtin_amdgcn_mfma_f32_16x16x32_bf16(
                        af[mi], bfr[ni], acc[mi][ni], 0, 0, 0);
        }
        asm volatile("" ::: "memory");
        FENCED_BARRIER();
    }
#undef STAGE_Q

    // ---- fused epilogue ----
    const int colbase = n0 + wc * 64;
    const int chunk = colbase >> 6;          // 0..35
    const int part = chunk / H_HEADS;        // 0=q 1=k 2=v
    const int h = chunk % H_HEADS;
    const int trow0 = m0 + wr * 32;

    if (part == 2) {
        const int seg = trow0 >> 9;
        const int key0 = (trow0 & 511) + l4 * 4;
        __hip_bfloat16* vdst = Vtb + ((size_t)(h * NSEG + seg) * DH) * SEG;
#pragma unroll
        for (int mi = 0; mi < 2; ++mi)
#pragma unroll
            for (int ni = 0; ni < 4; ++ni) {
                int d = ni * 16 + fr;
                union { __hip_bfloat16 h2[4]; ushort4 u; } o;
#pragma unroll
                for (int j = 0; j < 4; ++j) o.h2[j] = __float2bfloat16(acc[mi][ni][j]);
                *(ushort4*)(vdst + (size_t)d * SEG + key0 + mi * 16) = o.u;
            }
    } else {
        __hip_bfloat16* dst = (part == 0) ? Qb : Kb;
        const float scale = (part == 0) ? QSCALE : 1.0f;
#pragma unroll
        for (int mi = 0; mi < 2; ++mi)
#pragma unroll
            for (int j = 0; j < 4; ++j) {
                int t = trow0 + mi * 16 + l4 * 4 + j;
                const float2* tb = rtab + (size_t)t * 32;
                float2 cs0 = tb[fr];
                float2 cs1 = tb[16 + fr];
                __hip_bfloat16* op = dst + ((size_t)h * T_TOK + t) * DH;
                float x1, x2;
                x1 = acc[mi][0][j]; x2 = acc[mi][2][j];
                op[fr]      = __float2bfloat16((x1 * cs0.x - x2 * cs0.y) * scale);
                op[fr + 32] = __float2bfloat16((x2 * cs0.x + x1 * cs0.y) * scale);
                x1 = acc[mi][1][j]; x2 = acc[mi][3][j];
                op[16 + fr] = __float2bfloat16((x1 * cs1.x - x2 * cs1.y) * scale);
                op[48 + fr] = __float2bfloat16((x2 * cs1.x + x1 * cs1.y) * scale);
            }
    }
}

// ---------------------------------------------------------------------------
// Wo GEMM: 64x64 tile, 256 thr, 768 blocks; T2 swizzle + T1 XCD remap
// ---------------------------------------------------------------------------
__global__ __launch_bounds__(256) void gemm_wo64(const __hip_bfloat16* __restrict__ A,
                                                 const __hip_bfloat16* __restrict__ Bt,
                                                 float* __restrict__ C) {
    __shared__ __hip_bfloat16 As[2][64 * GBK];
    __shared__ __hip_bfloat16 Bs[2][64 * GBK];
    const int tid = threadIdx.x;
    const int lane = tid & 63;
    const int wid = tid >> 6;
    const int wr = wid >> 1, wc = wid & 1;
    const int orig = blockIdx.y * 12 + blockIdx.x;   // 0..767
    const int wg = (orig & 7) * 96 + (orig >> 3);
    const int m0 = (wg / 12) * 64;
    const int n0 = (wg % 12) * 64;
    const int K = D_MODEL;
    const int N = D_MODEL;

    f32x4_t acc[2][2];
#pragma unroll
    for (int i = 0; i < 2; ++i)
#pragma unroll
        for (int j = 0; j < 2; ++j) acc[i][j] = (f32x4_t){0.f, 0.f, 0.f, 0.f};

    const int lr = lane >> 3;
    const int gc = lane & 7;
    const int swzc = (gc ^ lr) << 3;
    const int fr = lane & 15;
    const int l4 = lane >> 4;
    const int fsw = fr & 7;

#define STAGE_W(buf_, k0_)                                                            \
    do {                                                                              \
        _Pragma("unroll")                                                             \
        for (int i_ = 0; i_ < 2; ++i_) {                                              \
            const int row_ = i_ * 32 + wid * 8;                                       \
            const __hip_bfloat16* ga_ = A + (size_t)(m0 + row_ + lr) * K + (k0_) + swzc; \
            __builtin_amdgcn_global_load_lds(                                         \
                (const __attribute__((address_space(1))) void*)ga_,                   \
                (__attribute__((address_space(3))) void*)(As[buf_] + row_ * GBK), 16, 0, 0); \
            const __hip_bfloat16* gb_ = Bt + (size_t)(n0 + row_ + lr) * K + (k0_) + swzc; \
            __builtin_amdgcn_global_load_lds(                                         \
                (const __attribute__((address_space(1))) void*)gb_,                   \
                (__attribute__((address_space(3))) void*)(Bs[buf_] + row_ * GBK), 16, 0, 0); \
        }                                                                             \
    } while (0)

    const int NKT = K / GBK;   // 12
    STAGE_W(0, 0);
    for (int kt = 0; kt < NKT; ++kt) {
        const int cur = kt & 1;
        if (kt < NKT - 1) {
            STAGE_W(cur ^ 1, (kt + 1) * GBK);
            asm volatile("s_waitcnt vmcnt(4)" ::: "memory");
        } else {
            asm volatile("s_waitcnt vmcnt(0)" ::: "memory");
        }
        FENCED_BARRIER();
#pragma unroll
        for (int kk = 0; kk < 2; ++kk) {
            const int rg = ((kk * 4 + l4) ^ fsw) << 3;
            bf16x8_t af[2], bfr[2];
#pragma unroll
            for (int mi = 0; mi < 2; ++mi)
                af[mi] = *(const bf16x8_t*)(As[cur] + (wr * 32 + mi * 16 + fr) * GBK + rg);
#pragma unroll
            for (int ni = 0; ni < 2; ++ni)
                bfr[ni] = *(const bf16x8_t*)(Bs[cur] + (wc * 32 + ni * 16 + fr) * GBK + rg);
#pragma unroll
            for (int mi = 0; mi < 2; ++mi)
#pragma unroll
                for (int ni = 0; ni < 2; ++ni)
                    acc[mi][ni] = __builtin_amdgcn_mfma_f32_16x16x32_bf16(
                        af[mi], bfr[ni], acc[mi][ni], 0, 0, 0);
        }
        asm volatile("" ::: "memory");
        FENCED_BARRIER();
    }
#undef STAGE_W

    float* Cb = C + (size_t)(m0 + wr * 32) * N + n0 + wc * 32;
#pragma unroll
    for (int mi = 0; mi < 2; ++mi)
#pragma unroll
        for (int ni = 0; ni < 2; ++ni)
#pragma unroll
            for (int j = 0; j < 4; ++j) {
                int r = mi * 16 + (lane >> 4) * 4 + j;
                Cb[(size_t)r * N + ni * 16 + fr] = acc[mi][ni][j];
            }
}

// ---------------- swapped-QK in-register-softmax flash attention ------------
__device__ __forceinline__ unsigned pk2(float a, float b) {
    unsigned ua = (unsigned)__bfloat16_as_ushort(__float2bfloat16(a));
    unsigned ub = (unsigned)__bfloat16_as_ushort(__float2bfloat16(b));
    return ua | (ub << 16);
}

__global__ __launch_bounds__(128) void attn_mfma(const __hip_bfloat16* __restrict__ Qb,
                                                 const __hip_bfloat16* __restrict__ Kb,
                                                 const __hip_bfloat16* __restrict__ Vtb,
                                                 __hip_bfloat16* __restrict__ attnb) {
    __shared__ __hip_bfloat16 KS[2][64 * 64];
    __shared__ __hip_bfloat16 VS[2][64 * 64];

    const int tid = threadIdx.x;
    const int lane = tid & 63;
    const int w = tid >> 6;
    const int hi = lane >> 5;
    const int l31 = lane & 31;
    const int orig = blockIdx.x;                 // 0..767
    const int wg = (orig & 7) * 96 + (orig >> 3);
    const int qt = wg & 7;
    const int hs = wg >> 3;
    const int h = hs % H_HEADS;
    const int seg = hs / H_HEADS;
    const int t0 = seg * SEG + qt * 64 + w * 32;

    const __hip_bfloat16* kb = Kb + ((size_t)h * T_TOK + seg * SEG) * DH;
    const __hip_bfloat16* vb = Vtb + (size_t)(h * NSEG + seg) * DH * SEG;

    bf16x8_t qf[4];
    {
        const __hip_bfloat16* qp = Qb + ((size_t)h * T_TOK + t0 + l31) * DH + hi * 8;
#pragma unroll
        for (int s = 0; s < 4; ++s) qf[s] = *(const bf16x8_t*)(qp + s * 16);
    }

    const int gr = lane >> 3;
    const int gc = lane & 7;

#pragma unroll
    for (int i = 0; i < 4; ++i) {
        int G = i * 128 + w * 64;
        int rk = (G >> 3) + gr;
        const __hip_bfloat16* sk = kb + (size_t)rk * DH + ((gc ^ (rk & 7)) << 3);
        __builtin_amdgcn_global_load_lds(
            (const __attribute__((address_space(1))) void*)sk,
            (__attribute__((address_space(3))) void*)(&KS[0][G * 8]), 16, 0, 0);
        const __hip_bfloat16* sv = vb + (size_t)rk * SEG + ((gc ^ (rk & 7)) << 3);
        __builtin_amdgcn_global_load_lds(
            (const __attribute__((address_space(1))) void*)sv,
            (__attribute__((address_space(3))) void*)(&VS[0][G * 8]), 16, 0, 0);
    }
    __syncthreads();

    f32x16_t ot[2];
#pragma unroll
    for (int n = 0; n < 2; ++n)
#pragma unroll
        for (int r = 0; r < 16; ++r) ot[n][r] = 0.f;
    float mrun = -3.0e38f, lrun = 0.f;

    for (int kv = 0; kv < 8; ++kv) {
        const int bb = kv & 1;
        if (kv < 7) {
#pragma unroll
            for (int i = 0; i < 4; ++i) {
                int G = i * 128 + w * 64;
                int rk = (G >> 3) + gr;
                const __hip_bfloat16* sk = kb + (size_t)((kv + 1) * 64 + rk) * DH + ((gc ^ (rk & 7)) << 3);
                __builtin_amdgcn_global_load_lds(
                    (const __attribute__((address_space(1))) void*)sk,
                    (__attribute__((address_space(3))) void*)(&KS[bb ^ 1][G * 8]), 16, 0, 0);
                const __hip_bfloat16* sv = vb + (size_t)rk * SEG + (kv + 1) * 64 + ((gc ^ (rk & 7)) << 3);
                __builtin_amdgcn_global_load_lds(
                    (const __attribute__((address_space(1))) void*)sv,
                    (__attribute__((address_space(3))) void*)(&VS[bb ^ 1][G * 8]), 16, 0, 0);
            }
        }

        f32x16_t st[2];
#pragma unroll
        for (int t = 0; t < 2; ++t)
#pragma unroll
            for (int r = 0; r < 16; ++r) st[t][r] = 0.f;
#pragma unroll
        for (int s = 0; s < 4; ++s) {
            int gk = s * 2 + hi;
            bf16x8_t k0 = *(const bf16x8_t*)(&KS[bb][l31 * 64 + ((gk ^ (l31 & 7)) << 3)]);
            bf16x8_t k1 = *(const bf16x8_t*)(&KS[bb][(32 + l31) * 64 + ((gk ^ (l31 & 7)) << 3)]);
            st[0] = __builtin_amdgcn_mfma_f32_32x32x16_bf16(k0, qf[s], st[0], 0, 0, 0);
            st[1] = __builtin_amdgcn_mfma_f32_32x32x16_bf16(k1, qf[s], st[1], 0, 0, 0);
        }

        float tmax = st[0][0];
#pragma unroll
        for (int r = 1; r < 16; ++r) tmax = fmaxf(tmax, st[0][r]);
#pragma unroll
        for (int r = 0; r < 16; ++r) tmax = fmaxf(tmax, st[1][r]);
        tmax = fmaxf(tmax, __shfl_xor(tmax, 32));

        if (!__all(tmax <= mrun + 8.0f)) {
            float mnew = fmaxf(mrun, tmax);
            float corr = exp2f(mrun - mnew);
            lrun *= corr;
#pragma unroll
            for (int n = 0; n < 2; ++n)
#pragma unroll
                for (int r = 0; r < 16; ++r) ot[n][r] *= corr;
            mrun = mnew;
        }
        float psum = 0.f;
#pragma unroll
        for (int t = 0; t < 2; ++t)
#pragma unroll
            for (int r = 0; r < 16; ++r) {
                float p = exp2f(st[t][r] - mrun);
                st[t][r] = p;
                psum += p;
            }
        psum += __shfl_xor(psum, 32);
        lrun += psum;

        bf16x8_t pf[4];
#pragma unroll
        for (int t = 0; t < 2; ++t) {
            unsigned wv[8], ov[8];
#pragma unroll
            for (int j = 0; j < 8; ++j) wv[j] = pk2(st[t][2 * j], st[t][2 * j + 1]);
#pragma unroll
            for (int j = 0; j < 8; ++j) ov[j] = (unsigned)__shfl_xor((int)wv[j], 32);
#pragma unroll
            for (int sh = 0; sh < 2; ++sh) {
                int b = sh * 4;
                union { unsigned u[4]; bf16x8_t v; } u8;
                u8.u[0] = hi ? ov[b + 2] : wv[b + 0];
                u8.u[1] = hi ? ov[b + 3] : wv[b + 1];
                u8.u[2] = hi ? wv[b + 2] : ov[b + 0];
                u8.u[3] = hi ? wv[b + 3] : ov[b + 1];
                pf[t * 2 + sh] = u8.v;
            }
        }

#pragma unroll
        for (int s = 0; s < 4; ++s) {
            int gk = s * 2 + hi;
            bf16x8_t v0 = *(const bf16x8_t*)(&VS[bb][l31 * 64 + ((gk ^ (l31 & 7)) << 3)]);
            bf16x8_t v1 = *(const bf16x8_t*)(&VS[bb][(32 + l31) * 64 + ((gk ^ (l31 & 7)) << 3)]);
            ot[0] = __builtin_amdgcn_mfma_f32_32x32x16_bf16(v0, pf[s], ot[0], 0, 0, 0);
            ot[1] = __builtin_amdgcn_mfma_f32_32x32x16_bf16(v1, pf[s], ot[1], 0, 0, 0);
        }
        __syncthreads();
    }

    float invl = 1.0f / lrun;
    ushort* Os = (ushort*)&KS[0][0];
    const int wbase = w * (64 * 33);
#pragma unroll
    for (int n = 0; n < 2; ++n)
#pragma unroll
        for (int r = 0; r < 16; ++r) {
            int d = n * 32 + (r & 3) + 8 * (r >> 2) + 4 * hi;
            Os[wbase + d * 33 + l31] = __bfloat16_as_ushort(__float2bfloat16(ot[n][r] * invl));
        }
    __syncthreads();
    {
        unsigned ow2[16];
#pragma unroll
        for (int j = 0; j < 16; ++j) {
            unsigned lo = Os[wbase + (hi * 32 + 2 * j) * 33 + l31];
            unsigned hh = Os[wbase + (hi * 32 + 2 * j + 1) * 33 + l31];
            ow2[j] = lo | (hh << 16);
        }
        uint4* gd = (uint4*)(attnb + (size_t)(t0 + l31) * D_MODEL + h * DH + hi * 32);
        gd[0] = make_uint4(ow2[0], ow2[1], ow2[2], ow2[3]);
        gd[1] = make_uint4(ow2[4], ow2[5], ow2[6], ow2[7]);
        gd[2] = make_uint4(ow2[8], ow2[9], ow2[10], ow2[11]);
        gd[3] = make_uint4(ow2[12], ow2[13], ow2[14], ow2[15]);
    }
}

// ---------------------------------------------------------------------------
extern "C" void kernel_launch(void* const* d_in, const int* in_sizes, int n_in,
                              void* d_out, int out_size, void* d_ws, size_t ws_size,
                              hipStream_t stream) {
    const float* hidden = (const float*)d_in[0];
    const float* Wqkv   = (const float*)d_in[1];
    const float* Wo     = (const float*)d_in[2];
    const int*   pos    = (const int*)d_in[3];

    char* ws = (char*)d_ws;
    __hip_bfloat16* Xb    = (__hip_bfloat16*)(ws);              // 6,291,456
    __hip_bfloat16* Wqkvt = (__hip_bfloat16*)(ws + 6291456);    // 3,538,944
    __hip_bfloat16* Wot   = (__hip_bfloat16*)(ws + 9830400);    // 1,179,648
    __hip_bfloat16* Qb    = (__hip_bfloat16*)(ws + 11010048);   // 6,291,456
    __hip_bfloat16* Kb    = (__hip_bfloat16*)(ws + 17301504);   // 6,291,456
    __hip_bfloat16* Vtb   = (__hip_bfloat16*)(ws + 23592960);   // 6,291,456
    __hip_bfloat16* attnb = (__hip_bfloat16*)(ws + 29884416);   // 6,291,456
    float2* rtab          = (float2*)(ws + 36175872);           // 1,048,576
    float* out = (float*)d_out;

    prep_inputs<<<4160, 256, 0, stream>>>(hidden, Wqkv, Wo, pos, Xb, Wqkvt, Wot, rtab);

    gemm_qkv_fused<<<dim3(QKV_LD / 128, T_TOK / 128), 512, 0, stream>>>(
        Xb, Wqkvt, rtab, Qb, Kb, Vtb);

    attn_mfma<<<768, 128, 0, stream>>>(Qb, Kb, Vtb, attnb);

    gemm_wo64<<<dim3(D_MODEL / 64, T_TOK / 64), 256, 0, stream>>>(
        attnb, Wot, out);
}